// Round 18
// baseline (252.603 us; speedup 1.0000x reference)
//
#include <hip/hip_runtime.h>

// Problem: B=1, L=4096, EMBED=1024, 16 heads x 64
static constexpr int L_SEQ = 4096;
static constexpr int EMBED = 1024;
static constexpr int HEADS = 16;
static constexpr int HD    = 64;

typedef unsigned short ushortT;
typedef __attribute__((ext_vector_type(8)))  short short8;   // 8 x bf16 (4 VGPR)
typedef __attribute__((ext_vector_type(4)))  float f32x4;
typedef __attribute__((ext_vector_type(4)))  unsigned uint4v;

#define LOG2E 1.4426950408889634f

__device__ __forceinline__ ushortT f2bf(float f) {
  unsigned u = __builtin_bit_cast(unsigned, f);
  u += 0x7fffu + ((u >> 16) & 1u);          // round-to-nearest-even
  return (ushortT)(u >> 16);
}
__device__ __forceinline__ float bf2f(ushortT s) {
  return __builtin_bit_cast(float, ((unsigned)s) << 16);
}
// v_cvt_pk_bf16_f32: two f32 -> u32 of 2x bf16 (lo=a, hi=b), RNE on CDNA4
__device__ __forceinline__ unsigned cvtpk(float a, float b) {
  unsigned r;
  asm("v_cvt_pk_bf16_f32 %0, %1, %2" : "=v"(r) : "v"(a), "v"(b));
  return r;
}

// async global->LDS, 16B/lane; LDS dest is wave-uniform base + lane*16.
#define GLOAD_LDS16(g, l) \
  __builtin_amdgcn_global_load_lds((const __attribute__((address_space(1))) void*)(g), \
                                   (__attribute__((address_space(3))) void*)(l), 16, 0, 0)

// ---------------- fp32 -> bf16 cast, 8 elems/thread ----------------
__global__ void cast_bf16_k(const float* __restrict__ in, ushortT* __restrict__ out, int n8) {
  int i = blockIdx.x * blockDim.x + threadIdx.x;
  if (i >= n8) return;
  const float4* p = (const float4*)in;
  float4 a = p[2 * i], b = p[2 * i + 1];
  uint4 o;
  o.x = (unsigned)f2bf(a.x) | ((unsigned)f2bf(a.y) << 16);
  o.y = (unsigned)f2bf(a.z) | ((unsigned)f2bf(a.w) << 16);
  o.z = (unsigned)f2bf(b.x) | ((unsigned)f2bf(b.y) << 16);
  o.w = (unsigned)f2bf(b.z) | ((unsigned)f2bf(b.w) << 16);
  ((uint4*)out)[i] = o;
}

// fused 4-weight cast (each weight 1M elements), dsts contiguous at out
__global__ void cast4_bf16_k(const float* __restrict__ a, const float* __restrict__ b,
                             const float* __restrict__ c, const float* __restrict__ d,
                             ushortT* __restrict__ out) {
  int idx = blockIdx.x * blockDim.x + threadIdx.x;   // 4 * 131072
  int w = idx >> 17, i = idx & 131071;
  const float* src = (w == 0) ? a : (w == 1) ? b : (w == 2) ? c : d;
  const float4* p = (const float4*)src;
  float4 x = p[2 * i], y = p[2 * i + 1];
  uint4 o;
  o.x = (unsigned)f2bf(x.x) | ((unsigned)f2bf(x.y) << 16);
  o.y = (unsigned)f2bf(x.z) | ((unsigned)f2bf(x.w) << 16);
  o.z = (unsigned)f2bf(y.x) | ((unsigned)f2bf(y.y) << 16);
  o.w = (unsigned)f2bf(y.z) | ((unsigned)f2bf(y.w) << 16);
  ((uint4*)(out + ((size_t)w << 20)))[i] = o;
}

// ---------------- log2(size) ----------------
__global__ void l2size_k(const float* __restrict__ sz, float* __restrict__ l2s, int n) {
  int i = blockIdx.x * blockDim.x + threadIdx.x;
  if (i < n) l2s[i] = __log2f(sz[i]);
}

// ---------------- GEMM: C[M,N] = A[M,K] @ B[N,K]^T + bias ----------------
struct GemmArgs { const ushortT* B; const float* bias; void* dst; int mode; };
// mode 0: Q -> bf16 [h][t][64] * 0.125   mode 1: K -> bf16 [h][t][64]
// mode 2: V -> bf16 [h][64][t] (transposed)      mode 3: fp32 [m][1024]

__global__ __launch_bounds__(256, 3) void gemm_bt_k(
    const ushortT* __restrict__ A, GemmArgs g0, GemmArgs g1, GemmArgs g2)
{
  constexpr int K = 1024;
  __shared__ __align__(16) ushortT As[128 * 64];
  __shared__ __align__(16) ushortT Bs[128 * 64];

  GemmArgs g = (blockIdx.y == 0) ? g0 : ((blockIdx.y == 1) ? g1 : g2);
  const ushortT* __restrict__ Bw = g.B;

  const int tid = threadIdx.x;
  const int wv = tid >> 6, ln = tid & 63;
  // XCD-locality decode (T1): nb = id&7 so each XCD serves ONE 128-col B-panel
  const int nb = blockIdx.x & 7, mb = blockIdx.x >> 3;      // 8 x 32 blocks
  const int m0 = mb * 128, n0 = nb * 128;
  const int wr = wv >> 1, wc = wv & 1;
  const int lrow = ln & 15, lq = ln >> 4;

  const int rstg = wv * 8 + (ln >> 3);
  const int ustg = (ln & 7) ^ (ln >> 3);

  f32x4 acc[4][4] = {};

  for (int kt = 0; kt < K; kt += 64) {
#pragma unroll
    for (int i = 0; i < 4; ++i) {
      int r = i * 32 + rstg;
      GLOAD_LDS16(A  + (size_t)(m0 + r) * K + kt + (ustg << 3), As + i * 2048 + wv * 512);
      GLOAD_LDS16(Bw + (size_t)(n0 + r) * K + kt + (ustg << 3), Bs + i * 2048 + wv * 512);
    }
    __syncthreads();
#pragma unroll
    for (int ks = 0; ks < 2; ++ks) {
      short8 a[4], b[4];
#pragma unroll
      for (int mi = 0; mi < 4; ++mi) {
        int ra = wr * 64 + mi * 16 + lrow;
        int u = (ks * 4 + lq) ^ (ra & 7);
        a[mi] = *(const short8*)(As + ra * 64 + (u << 3));
      }
#pragma unroll
      for (int ni = 0; ni < 4; ++ni) {
        int rb = wc * 64 + ni * 16 + lrow;
        int u = (ks * 4 + lq) ^ (rb & 7);
        b[ni] = *(const short8*)(Bs + rb * 64 + (u << 3));
      }
#pragma unroll
      for (int mi = 0; mi < 4; ++mi)
#pragma unroll
        for (int ni = 0; ni < 4; ++ni)
          acc[mi][ni] = __builtin_amdgcn_mfma_f32_16x16x32_bf16(a[mi], b[ni], acc[mi][ni], 0, 0, 0);
    }
    __syncthreads();
  }

  const int mode = g.mode;
  if (mode <= 1) {
    ushortT* dst = (ushortT*)g.dst;
    const float sc = (mode == 0) ? 0.125f : 1.0f;
#pragma unroll
    for (int ni = 0; ni < 4; ++ni) {
      int n = n0 + wc * 64 + ni * 16 + lrow;
      float bsv = g.bias[n];
      size_t base = ((size_t)(n >> 6) * L_SEQ) * HD + (n & 63);
#pragma unroll
      for (int mi = 0; mi < 4; ++mi)
#pragma unroll
        for (int r = 0; r < 4; ++r) {
          int m = m0 + wr * 64 + mi * 16 + lq * 4 + r;
          dst[base + (size_t)m * HD] = f2bf((acc[mi][ni][r] + bsv) * sc);
        }
    }
  } else if (mode == 2) {
    ushortT* dst = (ushortT*)g.dst;
#pragma unroll
    for (int ni = 0; ni < 4; ++ni) {
      int n = n0 + wc * 64 + ni * 16 + lrow;     // n == h*64+hd
      float bsv = g.bias[n];
      size_t base = (size_t)n * L_SEQ;
#pragma unroll
      for (int mi = 0; mi < 4; ++mi)
#pragma unroll
        for (int r = 0; r < 4; ++r) {
          int m = m0 + wr * 64 + mi * 16 + lq * 4 + r;
          dst[base + m] = f2bf(acc[mi][ni][r] + bsv);
        }
    }
  } else {
    float* dst = (float*)g.dst;
#pragma unroll
    for (int ni = 0; ni < 4; ++ni) {
      int n = n0 + wc * 64 + ni * 16 + lrow;
      float bsv = g.bias[n];
#pragma unroll
      for (int mi = 0; mi < 4; ++mi)
#pragma unroll
        for (int r = 0; r < 4; ++r) {
          int m = m0 + wr * 64 + mi * 16 + lq * 4 + r;
          dst[(size_t)m * EMBED + n] = acc[mi][ni][r] + bsv;
        }
    }
  }
}

// ---------------- flash attention (swapped 16x16, 64 q-rows per wave) --------
// R17 + one more doubling: each wave owns 64 q-rows (4 Q B-fragments, halves
// hf = 0..3 covering q = q0 + wv*64 + hf*16 + lrow). Every K/V fragment LDS
// read feeds FOUR MFMAs -> LDS read bytes per CU halve again (8.4 -> 4.2 MB).
// Block = 256 q x 4 waves, grid 256 (1 block/CU, 1 wave/SIMD) — TLP gone but
// 4 independent q-half chains give ILP. ~185 VGPR peak, all arrays statically
// unrolled (no dynamic indexing -> no scratch). Per-q-row math bitwise-
// identical to R15-R17.
__global__ __launch_bounds__(256, 1) void attn_k(
    const ushortT* __restrict__ Q,   // [16][4096][64], pre-scaled by 0.125
    const ushortT* __restrict__ Kb,  // [16][4096][64]
    const ushortT* __restrict__ Vt,  // [16][64][4096]
    const float*   __restrict__ l2s, // [4096] log2(size)
    ushortT* __restrict__ O)         // [4096][1024] bf16
{
  __shared__ __align__(16) ushortT Ks[2][64 * 64];
  __shared__ __align__(16) ushortT Vs[2][64 * 64];

  const int id = blockIdx.x;                 // 0..255
  const int xcd = id & 7, s = id >> 3;       // s: 0..31
  const int h  = xcd * 2 + (s >> 4);         // head (2 per XCD)
  const int q0 = (s & 15) * 256;             // q-tile base (256 rows/block)

  const int tid = threadIdx.x;
  const int wv = tid >> 6, ln = tid & 63;
  const int lrow = ln & 15, lq = ln >> 4;

  // Q fragments for four q-halves: hf covers q = q0 + wv*64 + hf*16 + lrow
  short8 qf[4][2];                 // [half][ks]
#pragma unroll
  for (int hf = 0; hf < 4; ++hf) {
    const ushortT* qp = Q + ((size_t)h * L_SEQ + q0 + wv * 64 + hf * 16 + lrow) * HD + lq * 8;
    qf[hf][0] = *(const short8*)qp;
    qf[hf][1] = *(const short8*)(qp + 32);
  }

  f32x4 o[4][4] = {};               // [hf][df]: o[hf][df][r] = O[16df+4lq+r][q]
  float mrun[4], lrun[4];
#pragma unroll
  for (int hf = 0; hf < 4; ++hf) { mrun[hf] = -1e30f; lrun[hf] = 0.f; }

  const int rstg = wv * 8 + (ln >> 3);
  const int ustg = (ln & 7) ^ (ln >> 3);

  const ushortT* kbase = Kb + ((size_t)h * L_SEQ + rstg) * HD + (ustg << 3);
  const ushortT* vbase = Vt + ((size_t)(h * HD) + rstg) * L_SEQ + (ustg << 3);

  auto STAGE = [&](int buf, int t0) {
#pragma unroll
    for (int i = 0; i < 2; ++i) {
      GLOAD_LDS16(kbase + t0 * 64 + i * (32 * HD),    &Ks[buf][i * 2048 + wv * 512]);
      GLOAD_LDS16(vbase + t0 + i * (32 * L_SEQ),      &Vs[buf][i * 2048 + wv * 512]);
    }
  };

  // loop-invariant V-read byte offsets (key groups {4lq,16+4lq,32+4lq,48+4lq},
  // slot = natural ^ (lrow&7); d = 16df+lrow so d&7 == lrow&7, df-invariant)
  const int sw = lrow & 7;
  const int vo0 = lrow * 128 + ((((lq >> 1))     ^ sw) << 4) + (lq & 1) * 8;
  const int vo1 = lrow * 128 + ((((lq >> 1) + 2) ^ sw) << 4) + (lq & 1) * 8;
  const int vo2 = lrow * 128 + ((((lq >> 1) + 4) ^ sw) << 4) + (lq & 1) * 8;
  const int vo3 = lrow * 128 + ((((lq >> 1) + 6) ^ sw) << 4) + (lq & 1) * 8;

  STAGE(0, 0);
  __syncthreads();                   // tile 0 resident

  constexpr int NT = L_SEQ / 64;
#pragma unroll 1
  for (int t = 0; t < NT; ++t) {
    const int cur = t & 1;
    if (t + 1 < NT) STAGE(cur ^ 1, (t + 1) * 64);   // overlaps entire compute
    const int t0 = t * 64;
    const ushortT* Kt = &Ks[cur][0];
    const char*    Vb = (const char*)&Vs[cur][0];

    // S^T = K Q for all 4 q-halves; each K-fragment read feeds 4 MFMAs
    f32x4 sfr[4][4] = {};            // [hf][f]
    __builtin_amdgcn_s_setprio(1);
#pragma unroll
    for (int ks = 0; ks < 2; ++ks) {
#pragma unroll
      for (int f = 0; f < 4; ++f) {
        int key = f * 16 + lrow;
        int u = (ks * 4 + lq) ^ (key & 7);
        short8 kb = *(const short8*)(Kt + key * 64 + (u << 3));
#pragma unroll
        for (int hf = 0; hf < 4; ++hf)
          sfr[hf][f] = __builtin_amdgcn_mfma_f32_16x16x32_bf16(kb, qf[hf][ks], sfr[hf][f], 0, 0, 0);
      }
    }
    __builtin_amdgcn_s_setprio(0);

    // base-2 logits + log2(size_key); key of sfr[hf][f][r] = 16f + 4lq + r
#pragma unroll
    for (int f = 0; f < 4; ++f) {
      f32x4 b = *(const f32x4*)(l2s + t0 + f * 16 + lq * 4);
#pragma unroll
      for (int hf = 0; hf < 4; ++hf)
#pragma unroll
        for (int r = 0; r < 4; ++r)
          sfr[hf][f][r] = sfr[hf][f][r] * LOG2E + b[r];
    }

    // softmax per half: in-lane tree + 2 cross-lane steps
    float alpha[4];
    bool noop = true;
#pragma unroll
    for (int hf = 0; hf < 4; ++hf) {
      float pm = fmaxf(fmaxf(fmaxf(sfr[hf][0][0], sfr[hf][0][1]), fmaxf(sfr[hf][0][2], sfr[hf][0][3])),
                       fmaxf(fmaxf(sfr[hf][1][0], sfr[hf][1][1]), fmaxf(sfr[hf][1][2], sfr[hf][1][3])));
      pm = fmaxf(pm, fmaxf(fmaxf(fmaxf(sfr[hf][2][0], sfr[hf][2][1]), fmaxf(sfr[hf][2][2], sfr[hf][2][3])),
                           fmaxf(fmaxf(sfr[hf][3][0], sfr[hf][3][1]), fmaxf(sfr[hf][3][2], sfr[hf][3][3]))));
      pm = fmaxf(pm, __shfl_xor(pm, 16));
      pm = fmaxf(pm, __shfl_xor(pm, 32));
      float mnew = fmaxf(mrun[hf], pm);
      alpha[hf] = __builtin_amdgcn_exp2f(mrun[hf] - mnew);
      mrun[hf] = mnew;

      float rs = 0.f;
#pragma unroll
      for (int f = 0; f < 4; ++f)
#pragma unroll
        for (int r = 0; r < 4; ++r) {
          float pv = __builtin_amdgcn_exp2f(sfr[hf][f][r] - mnew);
          sfr[hf][f][r] = pv;
          rs += pv;
        }
      rs += __shfl_xor(rs, 16);
      rs += __shfl_xor(rs, 32);
      lrun[hf] = lrun[hf] * alpha[hf] + rs;
      noop = noop && (alpha[hf] == 1.0f);
    }
    if (!__all(noop)) {              // skip O-rescale when no max growth
#pragma unroll
      for (int hf = 0; hf < 4; ++hf)
#pragma unroll
        for (int df = 0; df < 4; ++df)
#pragma unroll
          for (int r = 0; r < 4; ++r) o[hf][df][r] *= alpha[hf];
    }

    // P -> bf16 B-fragments in-register (kappa ordering), per half
    short8 pb[4][2];                 // [half][kgroup]
#pragma unroll
    for (int hf = 0; hf < 4; ++hf) {
      unsigned a0 = cvtpk(sfr[hf][0][0], sfr[hf][0][1]), a1 = cvtpk(sfr[hf][0][2], sfr[hf][0][3]);
      unsigned a2 = cvtpk(sfr[hf][1][0], sfr[hf][1][1]), a3 = cvtpk(sfr[hf][1][2], sfr[hf][1][3]);
      unsigned a4 = cvtpk(sfr[hf][2][0], sfr[hf][2][1]), a5 = cvtpk(sfr[hf][2][2], sfr[hf][2][3]);
      unsigned a6 = cvtpk(sfr[hf][3][0], sfr[hf][3][1]), a7 = cvtpk(sfr[hf][3][2], sfr[hf][3][3]);
      pb[hf][0] = __builtin_bit_cast(short8, (uint4v){a0, a1, a2, a3});  // keys 0..31
      pb[hf][1] = __builtin_bit_cast(short8, (uint4v){a4, a5, a6, a7});  // keys 32..63
    }

    // O^T += V P : each V-fragment read feeds 4 MFMAs (all q-halves)
    __builtin_amdgcn_s_setprio(1);
#pragma unroll
    for (int df = 0; df < 4; ++df) {
      const char* vr = Vb + df * 2048;
      uint2 a0 = *(const uint2*)(vr + vo0);
      uint2 a1 = *(const uint2*)(vr + vo1);
      short8 va = __builtin_bit_cast(short8, (uint4v){a0.x, a0.y, a1.x, a1.y});
#pragma unroll
      for (int hf = 0; hf < 4; ++hf)
        o[hf][df] = __builtin_amdgcn_mfma_f32_16x16x32_bf16(va, pb[hf][0], o[hf][df], 0, 0, 0);
      uint2 a2 = *(const uint2*)(vr + vo2);
      uint2 a3 = *(const uint2*)(vr + vo3);
      short8 vb2 = __builtin_bit_cast(short8, (uint4v){a2.x, a2.y, a3.x, a3.y});
#pragma unroll
      for (int hf = 0; hf < 4; ++hf)
        o[hf][df] = __builtin_amdgcn_mfma_f32_16x16x32_bf16(vb2, pb[hf][1], o[hf][df], 0, 0, 0);
    }
    __builtin_amdgcn_s_setprio(0);

    __syncthreads();                 // drains next-tile loads; frees cur buffer
  }

  // epilogue: O[q][h*64+d] = o^T / lrun; 4 packed 8B stores per half
#pragma unroll
  for (int hf = 0; hf < 4; ++hf) {
    float inv = 1.0f / lrun[hf];
    ushortT* ob = O + (size_t)(q0 + wv * 64 + hf * 16 + lrow) * EMBED + h * HD;
#pragma unroll
    for (int df = 0; df < 4; ++df) {
      uint2 w;
      w.x = (unsigned)f2bf(o[hf][df][0] * inv) | ((unsigned)f2bf(o[hf][df][1] * inv) << 16);
      w.y = (unsigned)f2bf(o[hf][df][2] * inv) | ((unsigned)f2bf(o[hf][df][3] * inv) << 16);
      *(uint2*)(ob + df * 16 + lq * 4) = w;
    }
  }
}

// ---------------- metric = mean over heads of K ----------------
__global__ void metric_k(const ushortT* __restrict__ Kb, float* __restrict__ out) {
  int idx = blockIdx.x * blockDim.x + threadIdx.x;   // t*8 + c8
  int t = idx >> 3, c8 = idx & 7;
  float acc[8] = {};
#pragma unroll
  for (int h = 0; h < HEADS; ++h) {
    short8 v = *(const short8*)(Kb + ((size_t)h * L_SEQ + t) * HD + c8 * 8);
#pragma unroll
    for (int j = 0; j < 8; ++j) acc[j] += bf2f((ushortT)v[j]);
  }
  float* dst = out + (size_t)t * HD + c8 * 8;
#pragma unroll
  for (int j = 0; j < 8; ++j) dst[j] = acc[j] * (1.0f / 16.0f);
}

extern "C" void kernel_launch(void* const* d_in, const int* in_sizes, int n_in,
                              void* d_out, int out_size, void* d_ws, size_t ws_size,
                              hipStream_t stream) {
  const float* hs = (const float*)d_in[0];
  const float* sz = (const float*)d_in[1];
  const float* wq = (const float*)d_in[2];
  const float* bq = (const float*)d_in[3];
  const float* wk = (const float*)d_in[4];
  const float* bk = (const float*)d_in[5];
  const float* wv = (const float*)d_in[6];
  const float* bv = (const float*)d_in[7];
  const float* wo = (const float*)d_in[8];
  const float* bo = (const float*)d_in[9];

  char* ws = (char*)d_ws;
  ushortT* hs_b = (ushortT*)(ws);                 // [4096][1024] bf16
  ushortT* wq_b = (ushortT*)(ws + (8u << 20));    // 4 weights bf16 (contiguous)
  ushortT* wk_b = wq_b + (1u << 20);
  ushortT* wv_b = wq_b + (2u << 20);
  ushortT* wo_b = wq_b + (3u << 20);
  ushortT* q_b  = (ushortT*)(ws + (16u << 20));   // [16][4096][64]
  ushortT* k_b  = (ushortT*)(ws + (24u << 20));   // [16][4096][64]
  ushortT* vt_b = (ushortT*)(ws + (32u << 20));   // [16][64][4096]
  ushortT* at_b = (ushortT*)(ws + (40u << 20));   // [4096][1024]
  float*   l2s  = (float*)(ws + (48u << 20));     // [4096]

  float* outp    = (float*)d_out;
  float* metricp = outp + (size_t)L_SEQ * EMBED;

  cast_bf16_k<<<L_SEQ * EMBED / 8 / 256, 256, 0, stream>>>(hs, hs_b, L_SEQ * EMBED / 8);
  cast4_bf16_k<<<2048, 256, 0, stream>>>(wq, wk, wv, wo, wq_b);
  l2size_k<<<L_SEQ / 256, 256, 0, stream>>>(sz, l2s, L_SEQ);

  GemmArgs aq{wq_b, bq, (void*)q_b, 0};
  GemmArgs ak{wk_b, bk, (void*)k_b, 1};
  GemmArgs av{wv_b, bv, (void*)vt_b, 2};
  gemm_bt_k<<<dim3(256, 3), 256, 0, stream>>>(hs_b, aq, ak, av);   // fused QKV

  metric_k<<<L_SEQ * 8 / 256, 256, 0, stream>>>(k_b, metricp);

  attn_k<<<256, 256, 0, stream>>>(q_b, k_b, vt_b, l2s, at_b);

  GemmArgs ao{wo_b, bo, (void*)outp, 3};
  gemm_bt_k<<<dim3(256, 1), 256, 0, stream>>>(at_b, ao, ao, ao);   // O projection
}

// Round 19
// 185.270 us; speedup vs baseline: 1.3634x; 1.3634x over previous
//
#include <hip/hip_runtime.h>

// Problem: B=1, L=4096, EMBED=1024, 16 heads x 64
static constexpr int L_SEQ = 4096;
static constexpr int EMBED = 1024;
static constexpr int HEADS = 16;
static constexpr int HD    = 64;

typedef unsigned short ushortT;
typedef __attribute__((ext_vector_type(8)))  short short8;   // 8 x bf16 (4 VGPR)
typedef __attribute__((ext_vector_type(4)))  float f32x4;
typedef __attribute__((ext_vector_type(4)))  unsigned uint4v;

#define LOG2E 1.4426950408889634f

__device__ __forceinline__ ushortT f2bf(float f) {
  unsigned u = __builtin_bit_cast(unsigned, f);
  u += 0x7fffu + ((u >> 16) & 1u);          // round-to-nearest-even
  return (ushortT)(u >> 16);
}
__device__ __forceinline__ float bf2f(ushortT s) {
  return __builtin_bit_cast(float, ((unsigned)s) << 16);
}
// v_cvt_pk_bf16_f32: two f32 -> u32 of 2x bf16 (lo=a, hi=b), RNE on CDNA4
__device__ __forceinline__ unsigned cvtpk(float a, float b) {
  unsigned r;
  asm("v_cvt_pk_bf16_f32 %0, %1, %2" : "=v"(r) : "v"(a), "v"(b));
  return r;
}

// async global->LDS, 16B/lane; LDS dest is wave-uniform base + lane*16.
#define GLOAD_LDS16(g, l) \
  __builtin_amdgcn_global_load_lds((const __attribute__((address_space(1))) void*)(g), \
                                   (__attribute__((address_space(3))) void*)(l), 16, 0, 0)

// ---------------- fp32 -> bf16 cast, 8 elems/thread ----------------
__global__ void cast_bf16_k(const float* __restrict__ in, ushortT* __restrict__ out, int n8) {
  int i = blockIdx.x * blockDim.x + threadIdx.x;
  if (i >= n8) return;
  const float4* p = (const float4*)in;
  float4 a = p[2 * i], b = p[2 * i + 1];
  uint4 o;
  o.x = (unsigned)f2bf(a.x) | ((unsigned)f2bf(a.y) << 16);
  o.y = (unsigned)f2bf(a.z) | ((unsigned)f2bf(a.w) << 16);
  o.z = (unsigned)f2bf(b.x) | ((unsigned)f2bf(b.y) << 16);
  o.w = (unsigned)f2bf(b.z) | ((unsigned)f2bf(b.w) << 16);
  ((uint4*)out)[i] = o;
}

// fused 4-weight cast (each weight 1M elements), dsts contiguous at out
__global__ void cast4_bf16_k(const float* __restrict__ a, const float* __restrict__ b,
                             const float* __restrict__ c, const float* __restrict__ d,
                             ushortT* __restrict__ out) {
  int idx = blockIdx.x * blockDim.x + threadIdx.x;   // 4 * 131072
  int w = idx >> 17, i = idx & 131071;
  const float* src = (w == 0) ? a : (w == 1) ? b : (w == 2) ? c : d;
  const float4* p = (const float4*)src;
  float4 x = p[2 * i], y = p[2 * i + 1];
  uint4 o;
  o.x = (unsigned)f2bf(x.x) | ((unsigned)f2bf(x.y) << 16);
  o.y = (unsigned)f2bf(x.z) | ((unsigned)f2bf(x.w) << 16);
  o.z = (unsigned)f2bf(y.x) | ((unsigned)f2bf(y.y) << 16);
  o.w = (unsigned)f2bf(y.z) | ((unsigned)f2bf(y.w) << 16);
  ((uint4*)(out + ((size_t)w << 20)))[i] = o;
}

// ---------------- log2(size) ----------------
__global__ void l2size_k(const float* __restrict__ sz, float* __restrict__ l2s, int n) {
  int i = blockIdx.x * blockDim.x + threadIdx.x;
  if (i < n) l2s[i] = __log2f(sz[i]);
}

// ---------------- GEMM: C[M,N] = A[M,K] @ B[N,K]^T + bias ----------------
struct GemmArgs { const ushortT* B; const float* bias; void* dst; int mode; };
// mode 0: Q -> bf16 [h][t][64] * 0.125   mode 1: K -> bf16 [h][t][64]
// mode 2: V -> bf16 [h][64][t] (transposed)      mode 3: fp32 [m][1024]

__global__ __launch_bounds__(256, 3) void gemm_bt_k(
    const ushortT* __restrict__ A, GemmArgs g0, GemmArgs g1, GemmArgs g2)
{
  constexpr int K = 1024;
  __shared__ __align__(16) ushortT As[128 * 64];
  __shared__ __align__(16) ushortT Bs[128 * 64];

  GemmArgs g = (blockIdx.y == 0) ? g0 : ((blockIdx.y == 1) ? g1 : g2);
  const ushortT* __restrict__ Bw = g.B;

  const int tid = threadIdx.x;
  const int wv = tid >> 6, ln = tid & 63;
  // XCD-locality decode (T1): nb = id&7 so each XCD serves ONE 128-col B-panel
  const int nb = blockIdx.x & 7, mb = blockIdx.x >> 3;      // 8 x 32 blocks
  const int m0 = mb * 128, n0 = nb * 128;
  const int wr = wv >> 1, wc = wv & 1;
  const int lrow = ln & 15, lq = ln >> 4;

  const int rstg = wv * 8 + (ln >> 3);
  const int ustg = (ln & 7) ^ (ln >> 3);

  f32x4 acc[4][4] = {};

  for (int kt = 0; kt < K; kt += 64) {
#pragma unroll
    for (int i = 0; i < 4; ++i) {
      int r = i * 32 + rstg;
      GLOAD_LDS16(A  + (size_t)(m0 + r) * K + kt + (ustg << 3), As + i * 2048 + wv * 512);
      GLOAD_LDS16(Bw + (size_t)(n0 + r) * K + kt + (ustg << 3), Bs + i * 2048 + wv * 512);
    }
    __syncthreads();
#pragma unroll
    for (int ks = 0; ks < 2; ++ks) {
      short8 a[4], b[4];
#pragma unroll
      for (int mi = 0; mi < 4; ++mi) {
        int ra = wr * 64 + mi * 16 + lrow;
        int u = (ks * 4 + lq) ^ (ra & 7);
        a[mi] = *(const short8*)(As + ra * 64 + (u << 3));
      }
#pragma unroll
      for (int ni = 0; ni < 4; ++ni) {
        int rb = wc * 64 + ni * 16 + lrow;
        int u = (ks * 4 + lq) ^ (rb & 7);
        b[ni] = *(const short8*)(Bs + rb * 64 + (u << 3));
      }
#pragma unroll
      for (int mi = 0; mi < 4; ++mi)
#pragma unroll
        for (int ni = 0; ni < 4; ++ni)
          acc[mi][ni] = __builtin_amdgcn_mfma_f32_16x16x32_bf16(a[mi], b[ni], acc[mi][ni], 0, 0, 0);
    }
    __syncthreads();
  }

  const int mode = g.mode;
  if (mode <= 1) {
    ushortT* dst = (ushortT*)g.dst;
    const float sc = (mode == 0) ? 0.125f : 1.0f;
#pragma unroll
    for (int ni = 0; ni < 4; ++ni) {
      int n = n0 + wc * 64 + ni * 16 + lrow;
      float bsv = g.bias[n];
      size_t base = ((size_t)(n >> 6) * L_SEQ) * HD + (n & 63);
#pragma unroll
      for (int mi = 0; mi < 4; ++mi)
#pragma unroll
        for (int r = 0; r < 4; ++r) {
          int m = m0 + wr * 64 + mi * 16 + lq * 4 + r;
          dst[base + (size_t)m * HD] = f2bf((acc[mi][ni][r] + bsv) * sc);
        }
    }
  } else if (mode == 2) {
    ushortT* dst = (ushortT*)g.dst;
#pragma unroll
    for (int ni = 0; ni < 4; ++ni) {
      int n = n0 + wc * 64 + ni * 16 + lrow;     // n == h*64+hd
      float bsv = g.bias[n];
      size_t base = (size_t)n * L_SEQ;
#pragma unroll
      for (int mi = 0; mi < 4; ++mi)
#pragma unroll
        for (int r = 0; r < 4; ++r) {
          int m = m0 + wr * 64 + mi * 16 + lq * 4 + r;
          dst[base + m] = f2bf(acc[mi][ni][r] + bsv);
        }
    }
  } else {
    float* dst = (float*)g.dst;
#pragma unroll
    for (int ni = 0; ni < 4; ++ni) {
      int n = n0 + wc * 64 + ni * 16 + lrow;
      float bsv = g.bias[n];
#pragma unroll
      for (int mi = 0; mi < 4; ++mi)
#pragma unroll
        for (int r = 0; r < 4; ++r) {
          int m = m0 + wr * 64 + mi * 16 + lq * 4 + r;
          dst[(size_t)m * EMBED + n] = acc[mi][ni][r] + bsv;
        }
    }
  }
}

// ---------------- flash attention (swapped 16x16, 32 q/wave, in-block KV-split)
// R17 structure + R19: block = 512 threads = 2 groups x 4 waves. Both groups
// cover the SAME 128 q-rows; group g processes KV tiles [32g, 32g+32) with its
// own double-buffered K/V LDS (total 64KB -> 2 blocks/CU = 16 waves/CU =
// 4 waves/SIMD, double R17's occupancy; total LDS bytes & VALU unchanged).
// After the loop the dead K/V buffers carry group 1's partials (m, l,
// unnormalized O in f32) and group 0 does the exact online-softmax merge.
__global__ __launch_bounds__(512, 4) void attn_k(
    const ushortT* __restrict__ Q,   // [16][4096][64], pre-scaled by 0.125
    const ushortT* __restrict__ Kb,  // [16][4096][64]
    const ushortT* __restrict__ Vt,  // [16][64][4096]
    const float*   __restrict__ l2s, // [4096] log2(size)
    ushortT* __restrict__ O)         // [4096][1024] bf16
{
  __shared__ __align__(16) ushortT Ks[2][2][64 * 64];   // [grp][buf]
  __shared__ __align__(16) ushortT Vs[2][2][64 * 64];   // [grp][buf]

  const int id = blockIdx.x;                 // 0..511
  const int xcd = id & 7, s = id >> 3;       // s: 0..63
  const int h  = xcd * 2 + (s >> 5);         // head (2 per XCD)
  const int q0 = (s & 31) * 128;             // q-tile base (128 rows/block)

  const int tid = threadIdx.x;
  const int wv  = tid >> 6;                  // 0..7
  const int grp = wv >> 2, wvg = wv & 3;     // KV-half group, wave-in-group
  const int ln  = tid & 63;
  const int lrow = ln & 15, lq = ln >> 4;

  // Q fragments for two q-halves: hf covers q = q0 + wvg*32 + hf*16 + lrow
  short8 qf[2][2];                 // [half][ks]
#pragma unroll
  for (int hf = 0; hf < 2; ++hf) {
    const ushortT* qp = Q + ((size_t)h * L_SEQ + q0 + wvg * 32 + hf * 16 + lrow) * HD + lq * 8;
    qf[hf][0] = *(const short8*)qp;
    qf[hf][1] = *(const short8*)(qp + 32);
  }

  f32x4 o0[4] = {}, o1[4] = {};     // O^T per half: o[df][r] = O[16df+4lq+r][q]
  float mrun0 = -1e30f, lrun0 = 0.f;
  float mrun1 = -1e30f, lrun1 = 0.f;

  const int rstg = wvg * 8 + (ln >> 3);
  const int ustg = (ln & 7) ^ (ln >> 3);

  const ushortT* kbase = Kb + ((size_t)h * L_SEQ + rstg) * HD + (ustg << 3);
  const ushortT* vbase = Vt + ((size_t)(h * HD) + rstg) * L_SEQ + (ustg << 3);

  auto STAGE = [&](int buf, int kt) {        // kt = global tile index
    const int t0 = kt * 64;
#pragma unroll
    for (int i = 0; i < 2; ++i) {
      GLOAD_LDS16(kbase + t0 * 64 + i * (32 * HD), &Ks[grp][buf][i * 2048 + wvg * 512]);
      GLOAD_LDS16(vbase + t0 + i * (32 * L_SEQ),   &Vs[grp][buf][i * 2048 + wvg * 512]);
    }
  };

  // loop-invariant V-read byte offsets (key groups {4lq,16+4lq,32+4lq,48+4lq},
  // slot = natural ^ (lrow&7); d = 16df+lrow so d&7 == lrow&7, df-invariant)
  const int sw = lrow & 7;
  const int vo0 = lrow * 128 + ((((lq >> 1))     ^ sw) << 4) + (lq & 1) * 8;
  const int vo1 = lrow * 128 + ((((lq >> 1) + 2) ^ sw) << 4) + (lq & 1) * 8;
  const int vo2 = lrow * 128 + ((((lq >> 1) + 4) ^ sw) << 4) + (lq & 1) * 8;
  const int vo3 = lrow * 128 + ((((lq >> 1) + 6) ^ sw) << 4) + (lq & 1) * 8;

  const int tbase = grp * 32;        // this group's KV tile range
  STAGE(0, tbase);
  __syncthreads();                   // tile 0 resident (both groups)

#pragma unroll 1
  for (int t = 0; t < 32; ++t) {
    const int cur = t & 1;
    if (t + 1 < 32) STAGE(cur ^ 1, tbase + t + 1);  // overlaps entire compute
    const int t0 = (tbase + t) * 64;
    const ushortT* Kt = &Ks[grp][cur][0];
    const char*    Vb = (const char*)&Vs[grp][cur][0];

    // S^T = K Q for both q-halves; each K-fragment read feeds 2 MFMAs
    f32x4 s0[4] = {}, s1[4] = {};
    __builtin_amdgcn_s_setprio(1);
#pragma unroll
    for (int ks = 0; ks < 2; ++ks) {
#pragma unroll
      for (int f = 0; f < 4; ++f) {
        int key = f * 16 + lrow;
        int u = (ks * 4 + lq) ^ (key & 7);
        short8 kb = *(const short8*)(Kt + key * 64 + (u << 3));
        s0[f] = __builtin_amdgcn_mfma_f32_16x16x32_bf16(kb, qf[0][ks], s0[f], 0, 0, 0);
        s1[f] = __builtin_amdgcn_mfma_f32_16x16x32_bf16(kb, qf[1][ks], s1[f], 0, 0, 0);
      }
    }
    __builtin_amdgcn_s_setprio(0);

    // base-2 logits + log2(size_key); key of s[f][r] = t0 + 16f + 4lq + r
#pragma unroll
    for (int f = 0; f < 4; ++f) {
      f32x4 b = *(const f32x4*)(l2s + t0 + f * 16 + lq * 4);
#pragma unroll
      for (int r = 0; r < 4; ++r) {
        s0[f][r] = s0[f][r] * LOG2E + b[r];
        s1[f][r] = s1[f][r] * LOG2E + b[r];
      }
    }

    // softmax per half: in-lane tree + 2 cross-lane steps (reduce over lq)
    float pm0 = fmaxf(fmaxf(fmaxf(s0[0][0], s0[0][1]), fmaxf(s0[0][2], s0[0][3])),
                      fmaxf(fmaxf(s0[1][0], s0[1][1]), fmaxf(s0[1][2], s0[1][3])));
    pm0 = fmaxf(pm0, fmaxf(fmaxf(fmaxf(s0[2][0], s0[2][1]), fmaxf(s0[2][2], s0[2][3])),
                           fmaxf(fmaxf(s0[3][0], s0[3][1]), fmaxf(s0[3][2], s0[3][3]))));
    float pm1 = fmaxf(fmaxf(fmaxf(s1[0][0], s1[0][1]), fmaxf(s1[0][2], s1[0][3])),
                      fmaxf(fmaxf(s1[1][0], s1[1][1]), fmaxf(s1[1][2], s1[1][3])));
    pm1 = fmaxf(pm1, fmaxf(fmaxf(fmaxf(s1[2][0], s1[2][1]), fmaxf(s1[2][2], s1[2][3])),
                           fmaxf(fmaxf(s1[3][0], s1[3][1]), fmaxf(s1[3][2], s1[3][3]))));
    pm0 = fmaxf(pm0, __shfl_xor(pm0, 16));
    pm0 = fmaxf(pm0, __shfl_xor(pm0, 32));
    pm1 = fmaxf(pm1, __shfl_xor(pm1, 16));
    pm1 = fmaxf(pm1, __shfl_xor(pm1, 32));
    float mnew0  = fmaxf(mrun0, pm0);
    float mnew1  = fmaxf(mrun1, pm1);
    float alpha0 = __builtin_amdgcn_exp2f(mrun0 - mnew0);
    float alpha1 = __builtin_amdgcn_exp2f(mrun1 - mnew1);
    mrun0 = mnew0; mrun1 = mnew1;

    float rs0 = 0.f, rs1 = 0.f;
#pragma unroll
    for (int f = 0; f < 4; ++f)
#pragma unroll
      for (int r = 0; r < 4; ++r) {
        float pv0 = __builtin_amdgcn_exp2f(s0[f][r] - mrun0);
        float pv1 = __builtin_amdgcn_exp2f(s1[f][r] - mrun1);
        s0[f][r] = pv0; rs0 += pv0;
        s1[f][r] = pv1; rs1 += pv1;
      }
    rs0 += __shfl_xor(rs0, 16);
    rs0 += __shfl_xor(rs0, 32);
    rs1 += __shfl_xor(rs1, 16);
    rs1 += __shfl_xor(rs1, 32);
    lrun0 = lrun0 * alpha0 + rs0;
    lrun1 = lrun1 * alpha1 + rs1;

    if (!__all(alpha0 == 1.0f && alpha1 == 1.0f)) {
#pragma unroll
      for (int df = 0; df < 4; ++df)
#pragma unroll
        for (int r = 0; r < 4; ++r) {
          o0[df][r] *= alpha0;
          o1[df][r] *= alpha1;
        }
    }

    // P -> bf16 B-fragments in-register (kappa ordering), per half
    short8 pb00, pb10, pb01, pb11;   // pb<kgroup><half>
    {
      unsigned a0 = cvtpk(s0[0][0], s0[0][1]), a1 = cvtpk(s0[0][2], s0[0][3]);
      unsigned a2 = cvtpk(s0[1][0], s0[1][1]), a3 = cvtpk(s0[1][2], s0[1][3]);
      unsigned a4 = cvtpk(s0[2][0], s0[2][1]), a5 = cvtpk(s0[2][2], s0[2][3]);
      unsigned a6 = cvtpk(s0[3][0], s0[3][1]), a7 = cvtpk(s0[3][2], s0[3][3]);
      pb00 = __builtin_bit_cast(short8, (uint4v){a0, a1, a2, a3});  // keys 0..31
      pb10 = __builtin_bit_cast(short8, (uint4v){a4, a5, a6, a7});  // keys 32..63
      unsigned b0 = cvtpk(s1[0][0], s1[0][1]), b1 = cvtpk(s1[0][2], s1[0][3]);
      unsigned b2 = cvtpk(s1[1][0], s1[1][1]), b3 = cvtpk(s1[1][2], s1[1][3]);
      unsigned b4 = cvtpk(s1[2][0], s1[2][1]), b5 = cvtpk(s1[2][2], s1[2][3]);
      unsigned b6 = cvtpk(s1[3][0], s1[3][1]), b7 = cvtpk(s1[3][2], s1[3][3]);
      pb01 = __builtin_bit_cast(short8, (uint4v){b0, b1, b2, b3});
      pb11 = __builtin_bit_cast(short8, (uint4v){b4, b5, b6, b7});
    }

    // O^T += V P : each V-fragment read feeds 2 MFMAs (both q-halves)
    __builtin_amdgcn_s_setprio(1);
#pragma unroll
    for (int df = 0; df < 4; ++df) {
      const char* vr = Vb + df * 2048;
      uint2 a0 = *(const uint2*)(vr + vo0);
      uint2 a1 = *(const uint2*)(vr + vo1);
      short8 va = __builtin_bit_cast(short8, (uint4v){a0.x, a0.y, a1.x, a1.y});
      o0[df] = __builtin_amdgcn_mfma_f32_16x16x32_bf16(va, pb00, o0[df], 0, 0, 0);
      o1[df] = __builtin_amdgcn_mfma_f32_16x16x32_bf16(va, pb01, o1[df], 0, 0, 0);
      uint2 a2 = *(const uint2*)(vr + vo2);
      uint2 a3 = *(const uint2*)(vr + vo3);
      short8 vb2 = __builtin_bit_cast(short8, (uint4v){a2.x, a2.y, a3.x, a3.y});
      o0[df] = __builtin_amdgcn_mfma_f32_16x16x32_bf16(vb2, pb10, o0[df], 0, 0, 0);
      o1[df] = __builtin_amdgcn_mfma_f32_16x16x32_bf16(vb2, pb11, o1[df], 0, 0, 0);
    }
    __builtin_amdgcn_s_setprio(0);

    __syncthreads();                 // drains next-tile loads; frees cur buffer
  }

  // ---- combine: group 1 publishes partials via the dead K/V LDS buffers ----
  float* Ob = (float*)&Ks[0][0][0];  // [128 q][64 d] fp32 = 32 KB
  float* Ml = (float*)&Vs[0][0][0];  // [128 q][2] (m, l)
  const int ql0 = wvg * 32 + lrow;   // q_local of half 0; half 1 = +16

  if (grp == 1) {
#pragma unroll
    for (int df = 0; df < 4; ++df) {
      *(f32x4*)(Ob + ql0 * 64 + df * 16 + lq * 4)        = o0[df];
      *(f32x4*)(Ob + (ql0 + 16) * 64 + df * 16 + lq * 4) = o1[df];
    }
    Ml[ql0 * 2] = mrun0;        Ml[ql0 * 2 + 1] = lrun0;
    Ml[(ql0 + 16) * 2] = mrun1; Ml[(ql0 + 16) * 2 + 1] = lrun1;
  }
  __syncthreads();
  if (grp == 0) {
    // merge half 0
    {
      float m1 = Ml[ql0 * 2], l1 = Ml[ql0 * 2 + 1];
      float m  = fmaxf(mrun0, m1);
      float w0 = __builtin_amdgcn_exp2f(mrun0 - m);
      float w1 = __builtin_amdgcn_exp2f(m1 - m);
      float inv = 1.0f / (lrun0 * w0 + l1 * w1);
      ushortT* ob = O + (size_t)(q0 + ql0) * EMBED + h * HD;
#pragma unroll
      for (int df = 0; df < 4; ++df) {
        f32x4 p1 = *(const f32x4*)(Ob + ql0 * 64 + df * 16 + lq * 4);
        uint2 w;
        w.x = (unsigned)f2bf((o0[df][0] * w0 + p1[0] * w1) * inv) |
              ((unsigned)f2bf((o0[df][1] * w0 + p1[1] * w1) * inv) << 16);
        w.y = (unsigned)f2bf((o0[df][2] * w0 + p1[2] * w1) * inv) |
              ((unsigned)f2bf((o0[df][3] * w0 + p1[3] * w1) * inv) << 16);
        *(uint2*)(ob + df * 16 + lq * 4) = w;
      }
    }
    // merge half 1
    {
      float m1 = Ml[(ql0 + 16) * 2], l1 = Ml[(ql0 + 16) * 2 + 1];
      float m  = fmaxf(mrun1, m1);
      float w0 = __builtin_amdgcn_exp2f(mrun1 - m);
      float w1 = __builtin_amdgcn_exp2f(m1 - m);
      float inv = 1.0f / (lrun1 * w0 + l1 * w1);
      ushortT* ob = O + (size_t)(q0 + ql0 + 16) * EMBED + h * HD;
#pragma unroll
      for (int df = 0; df < 4; ++df) {
        f32x4 p1 = *(const f32x4*)(Ob + (ql0 + 16) * 64 + df * 16 + lq * 4);
        uint2 w;
        w.x = (unsigned)f2bf((o1[df][0] * w0 + p1[0] * w1) * inv) |
              ((unsigned)f2bf((o1[df][1] * w0 + p1[1] * w1) * inv) << 16);
        w.y = (unsigned)f2bf((o1[df][2] * w0 + p1[2] * w1) * inv) |
              ((unsigned)f2bf((o1[df][3] * w0 + p1[3] * w1) * inv) << 16);
        *(uint2*)(ob + df * 16 + lq * 4) = w;
      }
    }
  }
}

// ---------------- metric = mean over heads of K ----------------
__global__ void metric_k(const ushortT* __restrict__ Kb, float* __restrict__ out) {
  int idx = blockIdx.x * blockDim.x + threadIdx.x;   // t*8 + c8
  int t = idx >> 3, c8 = idx & 7;
  float acc[8] = {};
#pragma unroll
  for (int h = 0; h < HEADS; ++h) {
    short8 v = *(const short8*)(Kb + ((size_t)h * L_SEQ + t) * HD + c8 * 8);
#pragma unroll
    for (int j = 0; j < 8; ++j) acc[j] += bf2f((ushortT)v[j]);
  }
  float* dst = out + (size_t)t * HD + c8 * 8;
#pragma unroll
  for (int j = 0; j < 8; ++j) dst[j] = acc[j] * (1.0f / 16.0f);
}

extern "C" void kernel_launch(void* const* d_in, const int* in_sizes, int n_in,
                              void* d_out, int out_size, void* d_ws, size_t ws_size,
                              hipStream_t stream) {
  const float* hs = (const float*)d_in[0];
  const float* sz = (const float*)d_in[1];
  const float* wq = (const float*)d_in[2];
  const float* bq = (const float*)d_in[3];
  const float* wk = (const float*)d_in[4];
  const float* bk = (const float*)d_in[5];
  const float* wv = (const float*)d_in[6];
  const float* bv = (const float*)d_in[7];
  const float* wo = (const float*)d_in[8];
  const float* bo = (const float*)d_in[9];

  char* ws = (char*)d_ws;
  ushortT* hs_b = (ushortT*)(ws);                 // [4096][1024] bf16
  ushortT* wq_b = (ushortT*)(ws + (8u << 20));    // 4 weights bf16 (contiguous)
  ushortT* wk_b = wq_b + (1u << 20);
  ushortT* wv_b = wq_b + (2u << 20);
  ushortT* wo_b = wq_b + (3u << 20);
  ushortT* q_b  = (ushortT*)(ws + (16u << 20));   // [16][4096][64]
  ushortT* k_b  = (ushortT*)(ws + (24u << 20));   // [16][4096][64]
  ushortT* vt_b = (ushortT*)(ws + (32u << 20));   // [16][64][4096]
  ushortT* at_b = (ushortT*)(ws + (40u << 20));   // [4096][1024]
  float*   l2s  = (float*)(ws + (48u << 20));     // [4096]

  float* outp    = (float*)d_out;
  float* metricp = outp + (size_t)L_SEQ * EMBED;

  cast_bf16_k<<<L_SEQ * EMBED / 8 / 256, 256, 0, stream>>>(hs, hs_b, L_SEQ * EMBED / 8);
  cast4_bf16_k<<<2048, 256, 0, stream>>>(wq, wk, wv, wo, wq_b);
  l2size_k<<<L_SEQ / 256, 256, 0, stream>>>(sz, l2s, L_SEQ);

  GemmArgs aq{wq_b, bq, (void*)q_b, 0};
  GemmArgs ak{wk_b, bk, (void*)k_b, 1};
  GemmArgs av{wv_b, bv, (void*)vt_b, 2};
  gemm_bt_k<<<dim3(256, 3), 256, 0, stream>>>(hs_b, aq, ak, av);   // fused QKV

  metric_k<<<L_SEQ * 8 / 256, 256, 0, stream>>>(k_b, metricp);

  attn_k<<<512, 512, 0, stream>>>(q_b, k_b, vt_b, l2s, at_b);

  GemmArgs ao{wo_b, bo, (void*)outp, 3};
  gemm_bt_k<<<dim3(256, 1), 256, 0, stream>>>(at_b, ao, ao, ao);   // O projection
}

// Round 20
// 179.078 us; speedup vs baseline: 1.4106x; 1.0346x over previous
//
#include <hip/hip_runtime.h>

// Problem: B=1, L=4096, EMBED=1024, 16 heads x 64
static constexpr int L_SEQ = 4096;
static constexpr int EMBED = 1024;
static constexpr int HEADS = 16;
static constexpr int HD    = 64;

typedef unsigned short ushortT;
typedef __attribute__((ext_vector_type(8)))  short short8;   // 8 x bf16 (4 VGPR)
typedef __attribute__((ext_vector_type(4)))  float f32x4;
typedef __attribute__((ext_vector_type(4)))  unsigned uint4v;

#define LOG2E 1.4426950408889634f

__device__ __forceinline__ ushortT f2bf(float f) {
  unsigned u = __builtin_bit_cast(unsigned, f);
  u += 0x7fffu + ((u >> 16) & 1u);          // round-to-nearest-even
  return (ushortT)(u >> 16);
}
__device__ __forceinline__ float bf2f(ushortT s) {
  return __builtin_bit_cast(float, ((unsigned)s) << 16);
}
// v_cvt_pk_bf16_f32: two f32 -> u32 of 2x bf16 (lo=a, hi=b), RNE on CDNA4
__device__ __forceinline__ unsigned cvtpk(float a, float b) {
  unsigned r;
  asm("v_cvt_pk_bf16_f32 %0, %1, %2" : "=v"(r) : "v"(a), "v"(b));
  return r;
}

// async global->LDS, 16B/lane; LDS dest is wave-uniform base + lane*16.
#define GLOAD_LDS16(g, l) \
  __builtin_amdgcn_global_load_lds((const __attribute__((address_space(1))) void*)(g), \
                                   (__attribute__((address_space(3))) void*)(l), 16, 0, 0)

// ---------------- fp32 -> bf16 cast, 8 elems/thread ----------------
__global__ void cast_bf16_k(const float* __restrict__ in, ushortT* __restrict__ out, int n8) {
  int i = blockIdx.x * blockDim.x + threadIdx.x;
  if (i >= n8) return;
  const float4* p = (const float4*)in;
  float4 a = p[2 * i], b = p[2 * i + 1];
  uint4 o;
  o.x = (unsigned)f2bf(a.x) | ((unsigned)f2bf(a.y) << 16);
  o.y = (unsigned)f2bf(a.z) | ((unsigned)f2bf(a.w) << 16);
  o.z = (unsigned)f2bf(b.x) | ((unsigned)f2bf(b.y) << 16);
  o.w = (unsigned)f2bf(b.z) | ((unsigned)f2bf(b.w) << 16);
  ((uint4*)out)[i] = o;
}

// fused 4-weight cast (each weight 1M elements), dsts contiguous at out
__global__ void cast4_bf16_k(const float* __restrict__ a, const float* __restrict__ b,
                             const float* __restrict__ c, const float* __restrict__ d,
                             ushortT* __restrict__ out) {
  int idx = blockIdx.x * blockDim.x + threadIdx.x;   // 4 * 131072
  int w = idx >> 17, i = idx & 131071;
  const float* src = (w == 0) ? a : (w == 1) ? b : (w == 2) ? c : d;
  const float4* p = (const float4*)src;
  float4 x = p[2 * i], y = p[2 * i + 1];
  uint4 o;
  o.x = (unsigned)f2bf(x.x) | ((unsigned)f2bf(x.y) << 16);
  o.y = (unsigned)f2bf(x.z) | ((unsigned)f2bf(x.w) << 16);
  o.z = (unsigned)f2bf(y.x) | ((unsigned)f2bf(y.y) << 16);
  o.w = (unsigned)f2bf(y.z) | ((unsigned)f2bf(y.w) << 16);
  ((uint4*)(out + ((size_t)w << 20)))[i] = o;
}

// ---------------- log2(size) ----------------
__global__ void l2size_k(const float* __restrict__ sz, float* __restrict__ l2s, int n) {
  int i = blockIdx.x * blockDim.x + threadIdx.x;
  if (i < n) l2s[i] = __log2f(sz[i]);
}

// ---------------- GEMM: C[M,N] = A[M,K] @ B[N,K]^T + bias ----------------
struct GemmArgs { const ushortT* B; const float* bias; void* dst; int mode; };
// mode 0: Q -> bf16 [h][t][64] * (0.125*LOG2E)   mode 1: K -> bf16 [h][t][64]
// mode 2: V -> bf16 [h][64][t] (transposed)

__global__ __launch_bounds__(256, 3) void gemm_bt_k(
    const ushortT* __restrict__ A, GemmArgs g0, GemmArgs g1, GemmArgs g2)
{
  constexpr int K = 1024;
  __shared__ __align__(16) ushortT As[128 * 64];
  __shared__ __align__(16) ushortT Bs[128 * 64];

  GemmArgs g = (blockIdx.y == 0) ? g0 : ((blockIdx.y == 1) ? g1 : g2);
  const ushortT* __restrict__ Bw = g.B;

  const int tid = threadIdx.x;
  const int wv = tid >> 6, ln = tid & 63;
  // XCD-locality decode (T1): nb = id&7 so each XCD serves ONE 128-col B-panel
  const int nb = blockIdx.x & 7, mb = blockIdx.x >> 3;      // 8 x 32 blocks
  const int m0 = mb * 128, n0 = nb * 128;
  const int wr = wv >> 1, wc = wv & 1;
  const int lrow = ln & 15, lq = ln >> 4;

  const int rstg = wv * 8 + (ln >> 3);
  const int ustg = (ln & 7) ^ (ln >> 3);

  f32x4 acc[4][4] = {};

  for (int kt = 0; kt < K; kt += 64) {
#pragma unroll
    for (int i = 0; i < 4; ++i) {
      int r = i * 32 + rstg;
      GLOAD_LDS16(A  + (size_t)(m0 + r) * K + kt + (ustg << 3), As + i * 2048 + wv * 512);
      GLOAD_LDS16(Bw + (size_t)(n0 + r) * K + kt + (ustg << 3), Bs + i * 2048 + wv * 512);
    }
    __syncthreads();
#pragma unroll
    for (int ks = 0; ks < 2; ++ks) {
      short8 a[4], b[4];
#pragma unroll
      for (int mi = 0; mi < 4; ++mi) {
        int ra = wr * 64 + mi * 16 + lrow;
        int u = (ks * 4 + lq) ^ (ra & 7);
        a[mi] = *(const short8*)(As + ra * 64 + (u << 3));
      }
#pragma unroll
      for (int ni = 0; ni < 4; ++ni) {
        int rb = wc * 64 + ni * 16 + lrow;
        int u = (ks * 4 + lq) ^ (rb & 7);
        b[ni] = *(const short8*)(Bs + rb * 64 + (u << 3));
      }
#pragma unroll
      for (int mi = 0; mi < 4; ++mi)
#pragma unroll
        for (int ni = 0; ni < 4; ++ni)
          acc[mi][ni] = __builtin_amdgcn_mfma_f32_16x16x32_bf16(a[mi], b[ni], acc[mi][ni], 0, 0, 0);
    }
    __syncthreads();
  }

  const int mode = g.mode;
  if (mode <= 1) {
    ushortT* dst = (ushortT*)g.dst;
    const float sc = (mode == 0) ? (0.125f * LOG2E) : 1.0f;
#pragma unroll
    for (int ni = 0; ni < 4; ++ni) {
      int n = n0 + wc * 64 + ni * 16 + lrow;
      float bsv = g.bias[n];
      size_t base = ((size_t)(n >> 6) * L_SEQ) * HD + (n & 63);
#pragma unroll
      for (int mi = 0; mi < 4; ++mi)
#pragma unroll
        for (int r = 0; r < 4; ++r) {
          int m = m0 + wr * 64 + mi * 16 + lq * 4 + r;
          dst[base + (size_t)m * HD] = f2bf((acc[mi][ni][r] + bsv) * sc);
        }
    }
  } else {
    ushortT* dst = (ushortT*)g.dst;
#pragma unroll
    for (int ni = 0; ni < 4; ++ni) {
      int n = n0 + wc * 64 + ni * 16 + lrow;     // n == h*64+hd
      float bsv = g.bias[n];
      size_t base = (size_t)n * L_SEQ;
#pragma unroll
      for (int mi = 0; mi < 4; ++mi)
#pragma unroll
        for (int r = 0; r < 4; ++r) {
          int m = m0 + wr * 64 + mi * 16 + lq * 4 + r;
          dst[base + m] = f2bf(acc[mi][ni][r] + bsv);
        }
    }
  }
}

// ---------------- O-projection GEMM: 64x128 tile, fp32 out ----------------
// 512 blocks = 2 blocks/CU (the 128x128 version ran 256 blocks = 1/CU with
// zero inter-block overlap). LDS 8K + 16K = 24KB.
__global__ __launch_bounds__(256, 2) void gemm_o64_k(
    const ushortT* __restrict__ A, const ushortT* __restrict__ Bw,
    const float* __restrict__ bias, float* __restrict__ dst)
{
  constexpr int K = 1024;
  __shared__ __align__(16) ushortT As[64 * 64];
  __shared__ __align__(16) ushortT Bs[128 * 64];

  const int tid = threadIdx.x;
  const int wv = tid >> 6, ln = tid & 63;
  const int nb = blockIdx.x & 7, mb = blockIdx.x >> 3;      // 8 x 64 blocks
  const int m0 = mb * 64, n0 = nb * 128;
  const int wr = wv >> 1, wc = wv & 1;
  const int lrow = ln & 15, lq = ln >> 4;

  const int rstg = wv * 8 + (ln >> 3);
  const int ustg = (ln & 7) ^ (ln >> 3);

  f32x4 acc[2][4] = {};

  for (int kt = 0; kt < K; kt += 64) {
#pragma unroll
    for (int i = 0; i < 2; ++i) {
      int r = i * 32 + rstg;
      GLOAD_LDS16(A + (size_t)(m0 + r) * K + kt + (ustg << 3), As + i * 2048 + wv * 512);
    }
#pragma unroll
    for (int i = 0; i < 4; ++i) {
      int r = i * 32 + rstg;
      GLOAD_LDS16(Bw + (size_t)(n0 + r) * K + kt + (ustg << 3), Bs + i * 2048 + wv * 512);
    }
    __syncthreads();
#pragma unroll
    for (int ks = 0; ks < 2; ++ks) {
      short8 a[2], b[4];
#pragma unroll
      for (int mi = 0; mi < 2; ++mi) {
        int ra = wr * 32 + mi * 16 + lrow;
        int u = (ks * 4 + lq) ^ (ra & 7);
        a[mi] = *(const short8*)(As + ra * 64 + (u << 3));
      }
#pragma unroll
      for (int ni = 0; ni < 4; ++ni) {
        int rb = wc * 64 + ni * 16 + lrow;
        int u = (ks * 4 + lq) ^ (rb & 7);
        b[ni] = *(const short8*)(Bs + rb * 64 + (u << 3));
      }
#pragma unroll
      for (int mi = 0; mi < 2; ++mi)
#pragma unroll
        for (int ni = 0; ni < 4; ++ni)
          acc[mi][ni] = __builtin_amdgcn_mfma_f32_16x16x32_bf16(a[mi], b[ni], acc[mi][ni], 0, 0, 0);
    }
    __syncthreads();
  }

#pragma unroll
  for (int ni = 0; ni < 4; ++ni) {
    int n = n0 + wc * 64 + ni * 16 + lrow;
    float bsv = bias[n];
#pragma unroll
    for (int mi = 0; mi < 2; ++mi)
#pragma unroll
      for (int r = 0; r < 4; ++r) {
        int m = m0 + wr * 32 + mi * 16 + lq * 4 + r;
        dst[(size_t)m * EMBED + n] = acc[mi][ni][r] + bsv;
      }
  }
}

// ---------------- flash attention (swapped 16x16, 32 q/wave, in-block KV-split)
// R19 structure + R20: bias-in-accumulator. Q is pre-scaled by 0.125*LOG2E in
// the projection, and the S accumulators are INITIALIZED with the log2(size)
// bias vector (MFMA C-in), so S*log2e + bias comes straight out of the matrix
// pipe — the per-tile 32-FMA bias pass is gone.
__global__ __launch_bounds__(512, 4) void attn_k(
    const ushortT* __restrict__ Q,   // [16][4096][64], pre-scaled 0.125*LOG2E
    const ushortT* __restrict__ Kb,  // [16][4096][64]
    const ushortT* __restrict__ Vt,  // [16][64][4096]
    const float*   __restrict__ l2s, // [4096] log2(size)
    ushortT* __restrict__ O)         // [4096][1024] bf16
{
  __shared__ __align__(16) ushortT Ks[2][2][64 * 64];   // [grp][buf]
  __shared__ __align__(16) ushortT Vs[2][2][64 * 64];   // [grp][buf]

  const int id = blockIdx.x;                 // 0..511
  const int xcd = id & 7, s = id >> 3;       // s: 0..63
  const int h  = xcd * 2 + (s >> 5);         // head (2 per XCD)
  const int q0 = (s & 31) * 128;             // q-tile base (128 rows/block)

  const int tid = threadIdx.x;
  const int wv  = tid >> 6;                  // 0..7
  const int grp = wv >> 2, wvg = wv & 3;     // KV-half group, wave-in-group
  const int ln  = tid & 63;
  const int lrow = ln & 15, lq = ln >> 4;

  // Q fragments for two q-halves: hf covers q = q0 + wvg*32 + hf*16 + lrow
  short8 qf[2][2];                 // [half][ks]
#pragma unroll
  for (int hf = 0; hf < 2; ++hf) {
    const ushortT* qp = Q + ((size_t)h * L_SEQ + q0 + wvg * 32 + hf * 16 + lrow) * HD + lq * 8;
    qf[hf][0] = *(const short8*)qp;
    qf[hf][1] = *(const short8*)(qp + 32);
  }

  f32x4 o0[4] = {}, o1[4] = {};     // O^T per half: o[df][r] = O[16df+4lq+r][q]
  float mrun0 = -1e30f, lrun0 = 0.f;
  float mrun1 = -1e30f, lrun1 = 0.f;

  const int rstg = wvg * 8 + (ln >> 3);
  const int ustg = (ln & 7) ^ (ln >> 3);

  const ushortT* kbase = Kb + ((size_t)h * L_SEQ + rstg) * HD + (ustg << 3);
  const ushortT* vbase = Vt + ((size_t)(h * HD) + rstg) * L_SEQ + (ustg << 3);

  auto STAGE = [&](int buf, int kt) {        // kt = global tile index
    const int t0 = kt * 64;
#pragma unroll
    for (int i = 0; i < 2; ++i) {
      GLOAD_LDS16(kbase + t0 * 64 + i * (32 * HD), &Ks[grp][buf][i * 2048 + wvg * 512]);
      GLOAD_LDS16(vbase + t0 + i * (32 * L_SEQ),   &Vs[grp][buf][i * 2048 + wvg * 512]);
    }
  };

  // loop-invariant V-read byte offsets (key groups {4lq,16+4lq,32+4lq,48+4lq},
  // slot = natural ^ (lrow&7); d = 16df+lrow so d&7 == lrow&7, df-invariant)
  const int sw = lrow & 7;
  const int vo0 = lrow * 128 + ((((lq >> 1))     ^ sw) << 4) + (lq & 1) * 8;
  const int vo1 = lrow * 128 + ((((lq >> 1) + 2) ^ sw) << 4) + (lq & 1) * 8;
  const int vo2 = lrow * 128 + ((((lq >> 1) + 4) ^ sw) << 4) + (lq & 1) * 8;
  const int vo3 = lrow * 128 + ((((lq >> 1) + 6) ^ sw) << 4) + (lq & 1) * 8;

  const int tbase = grp * 32;        // this group's KV tile range
  STAGE(0, tbase);
  __syncthreads();                   // tile 0 resident (both groups)

#pragma unroll 1
  for (int t = 0; t < 32; ++t) {
    const int cur = t & 1;
    if (t + 1 < 32) STAGE(cur ^ 1, tbase + t + 1);  // overlaps entire compute
    const int t0 = (tbase + t) * 64;
    const ushortT* Kt = &Ks[grp][cur][0];
    const char*    Vb = (const char*)&Vs[grp][cur][0];

    // S^T accumulators initialized with bias (key of s[f][r] = t0+16f+4lq+r);
    // Q carries the LOG2E scale, so MFMA output = S*log2e + bias directly.
    f32x4 s0[4], s1[4];
#pragma unroll
    for (int f = 0; f < 4; ++f) {
      f32x4 b = *(const f32x4*)(l2s + t0 + f * 16 + lq * 4);
      s0[f] = b; s1[f] = b;
    }

    __builtin_amdgcn_s_setprio(1);
#pragma unroll
    for (int ks = 0; ks < 2; ++ks) {
#pragma unroll
      for (int f = 0; f < 4; ++f) {
        int key = f * 16 + lrow;
        int u = (ks * 4 + lq) ^ (key & 7);
        short8 kb = *(const short8*)(Kt + key * 64 + (u << 3));
        s0[f] = __builtin_amdgcn_mfma_f32_16x16x32_bf16(kb, qf[0][ks], s0[f], 0, 0, 0);
        s1[f] = __builtin_amdgcn_mfma_f32_16x16x32_bf16(kb, qf[1][ks], s1[f], 0, 0, 0);
      }
    }
    __builtin_amdgcn_s_setprio(0);

    // softmax per half: in-lane tree + 2 cross-lane steps (reduce over lq)
    float pm0 = fmaxf(fmaxf(fmaxf(s0[0][0], s0[0][1]), fmaxf(s0[0][2], s0[0][3])),
                      fmaxf(fmaxf(s0[1][0], s0[1][1]), fmaxf(s0[1][2], s0[1][3])));
    pm0 = fmaxf(pm0, fmaxf(fmaxf(fmaxf(s0[2][0], s0[2][1]), fmaxf(s0[2][2], s0[2][3])),
                           fmaxf(fmaxf(s0[3][0], s0[3][1]), fmaxf(s0[3][2], s0[3][3]))));
    float pm1 = fmaxf(fmaxf(fmaxf(s1[0][0], s1[0][1]), fmaxf(s1[0][2], s1[0][3])),
                      fmaxf(fmaxf(s1[1][0], s1[1][1]), fmaxf(s1[1][2], s1[1][3])));
    pm1 = fmaxf(pm1, fmaxf(fmaxf(fmaxf(s1[2][0], s1[2][1]), fmaxf(s1[2][2], s1[2][3])),
                           fmaxf(fmaxf(s1[3][0], s1[3][1]), fmaxf(s1[3][2], s1[3][3]))));
    pm0 = fmaxf(pm0, __shfl_xor(pm0, 16));
    pm0 = fmaxf(pm0, __shfl_xor(pm0, 32));
    pm1 = fmaxf(pm1, __shfl_xor(pm1, 16));
    pm1 = fmaxf(pm1, __shfl_xor(pm1, 32));
    float mnew0  = fmaxf(mrun0, pm0);
    float mnew1  = fmaxf(mrun1, pm1);
    float alpha0 = __builtin_amdgcn_exp2f(mrun0 - mnew0);
    float alpha1 = __builtin_amdgcn_exp2f(mrun1 - mnew1);
    mrun0 = mnew0; mrun1 = mnew1;

    float rs0 = 0.f, rs1 = 0.f;
#pragma unroll
    for (int f = 0; f < 4; ++f)
#pragma unroll
      for (int r = 0; r < 4; ++r) {
        float pv0 = __builtin_amdgcn_exp2f(s0[f][r] - mrun0);
        float pv1 = __builtin_amdgcn_exp2f(s1[f][r] - mrun1);
        s0[f][r] = pv0; rs0 += pv0;
        s1[f][r] = pv1; rs1 += pv1;
      }
    rs0 += __shfl_xor(rs0, 16);
    rs0 += __shfl_xor(rs0, 32);
    rs1 += __shfl_xor(rs1, 16);
    rs1 += __shfl_xor(rs1, 32);
    lrun0 = lrun0 * alpha0 + rs0;
    lrun1 = lrun1 * alpha1 + rs1;

    if (!__all(alpha0 == 1.0f && alpha1 == 1.0f)) {
#pragma unroll
      for (int df = 0; df < 4; ++df)
#pragma unroll
        for (int r = 0; r < 4; ++r) {
          o0[df][r] *= alpha0;
          o1[df][r] *= alpha1;
        }
    }

    // P -> bf16 B-fragments in-register (kappa ordering), per half
    short8 pb00, pb10, pb01, pb11;   // pb<kgroup><half>
    {
      unsigned a0 = cvtpk(s0[0][0], s0[0][1]), a1 = cvtpk(s0[0][2], s0[0][3]);
      unsigned a2 = cvtpk(s0[1][0], s0[1][1]), a3 = cvtpk(s0[1][2], s0[1][3]);
      unsigned a4 = cvtpk(s0[2][0], s0[2][1]), a5 = cvtpk(s0[2][2], s0[2][3]);
      unsigned a6 = cvtpk(s0[3][0], s0[3][1]), a7 = cvtpk(s0[3][2], s0[3][3]);
      pb00 = __builtin_bit_cast(short8, (uint4v){a0, a1, a2, a3});  // keys 0..31
      pb10 = __builtin_bit_cast(short8, (uint4v){a4, a5, a6, a7});  // keys 32..63
      unsigned b0 = cvtpk(s1[0][0], s1[0][1]), b1 = cvtpk(s1[0][2], s1[0][3]);
      unsigned b2 = cvtpk(s1[1][0], s1[1][1]), b3 = cvtpk(s1[1][2], s1[1][3]);
      unsigned b4 = cvtpk(s1[2][0], s1[2][1]), b5 = cvtpk(s1[2][2], s1[2][3]);
      unsigned b6 = cvtpk(s1[3][0], s1[3][1]), b7 = cvtpk(s1[3][2], s1[3][3]);
      pb01 = __builtin_bit_cast(short8, (uint4v){b0, b1, b2, b3});
      pb11 = __builtin_bit_cast(short8, (uint4v){b4, b5, b6, b7});
    }

    // O^T += V P : each V-fragment read feeds 2 MFMAs (both q-halves)
    __builtin_amdgcn_s_setprio(1);
#pragma unroll
    for (int df = 0; df < 4; ++df) {
      const char* vr = Vb + df * 2048;
      uint2 a0 = *(const uint2*)(vr + vo0);
      uint2 a1 = *(const uint2*)(vr + vo1);
      short8 va = __builtin_bit_cast(short8, (uint4v){a0.x, a0.y, a1.x, a1.y});
      o0[df] = __builtin_amdgcn_mfma_f32_16x16x32_bf16(va, pb00, o0[df], 0, 0, 0);
      o1[df] = __builtin_amdgcn_mfma_f32_16x16x32_bf16(va, pb01, o1[df], 0, 0, 0);
      uint2 a2 = *(const uint2*)(vr + vo2);
      uint2 a3 = *(const uint2*)(vr + vo3);
      short8 vb2 = __builtin_bit_cast(short8, (uint4v){a2.x, a2.y, a3.x, a3.y});
      o0[df] = __builtin_amdgcn_mfma_f32_16x16x32_bf16(vb2, pb10, o0[df], 0, 0, 0);
      o1[df] = __builtin_amdgcn_mfma_f32_16x16x32_bf16(vb2, pb11, o1[df], 0, 0, 0);
    }
    __builtin_amdgcn_s_setprio(0);

    __syncthreads();                 // drains next-tile loads; frees cur buffer
  }

  // ---- combine: group 1 publishes partials via the dead K/V LDS buffers ----
  float* Ob = (float*)&Ks[0][0][0];  // [128 q][64 d] fp32 = 32 KB
  float* Ml = (float*)&Vs[0][0][0];  // [128 q][2] (m, l)
  const int ql0 = wvg * 32 + lrow;   // q_local of half 0; half 1 = +16

  if (grp == 1) {
#pragma unroll
    for (int df = 0; df < 4; ++df) {
      *(f32x4*)(Ob + ql0 * 64 + df * 16 + lq * 4)        = o0[df];
      *(f32x4*)(Ob + (ql0 + 16) * 64 + df * 16 + lq * 4) = o1[df];
    }
    Ml[ql0 * 2] = mrun0;        Ml[ql0 * 2 + 1] = lrun0;
    Ml[(ql0 + 16) * 2] = mrun1; Ml[(ql0 + 16) * 2 + 1] = lrun1;
  }
  __syncthreads();
  if (grp == 0) {
    // merge half 0
    {
      float m1 = Ml[ql0 * 2], l1 = Ml[ql0 * 2 + 1];
      float m  = fmaxf(mrun0, m1);
      float w0 = __builtin_amdgcn_exp2f(mrun0 - m);
      float w1 = __builtin_amdgcn_exp2f(m1 - m);
      float inv = 1.0f / (lrun0 * w0 + l1 * w1);
      ushortT* ob = O + (size_t)(q0 + ql0) * EMBED + h * HD;
#pragma unroll
      for (int df = 0; df < 4; ++df) {
        f32x4 p1 = *(const f32x4*)(Ob + ql0 * 64 + df * 16 + lq * 4);
        uint2 w;
        w.x = (unsigned)f2bf((o0[df][0] * w0 + p1[0] * w1) * inv) |
              ((unsigned)f2bf((o0[df][1] * w0 + p1[1] * w1) * inv) << 16);
        w.y = (unsigned)f2bf((o0[df][2] * w0 + p1[2] * w1) * inv) |
              ((unsigned)f2bf((o0[df][3] * w0 + p1[3] * w1) * inv) << 16);
        *(uint2*)(ob + df * 16 + lq * 4) = w;
      }
    }
    // merge half 1
    {
      float m1 = Ml[(ql0 + 16) * 2], l1 = Ml[(ql0 + 16) * 2 + 1];
      float m  = fmaxf(mrun1, m1);
      float w0 = __builtin_amdgcn_exp2f(mrun1 - m);
      float w1 = __builtin_amdgcn_exp2f(m1 - m);
      float inv = 1.0f / (lrun1 * w0 + l1 * w1);
      ushortT* ob = O + (size_t)(q0 + ql0 + 16) * EMBED + h * HD;
#pragma unroll
      for (int df = 0; df < 4; ++df) {
        f32x4 p1 = *(const f32x4*)(Ob + (ql0 + 16) * 64 + df * 16 + lq * 4);
        uint2 w;
        w.x = (unsigned)f2bf((o1[df][0] * w0 + p1[0] * w1) * inv) |
              ((unsigned)f2bf((o1[df][1] * w0 + p1[1] * w1) * inv) << 16);
        w.y = (unsigned)f2bf((o1[df][2] * w0 + p1[2] * w1) * inv) |
              ((unsigned)f2bf((o1[df][3] * w0 + p1[3] * w1) * inv) << 16);
        *(uint2*)(ob + df * 16 + lq * 4) = w;
      }
    }
  }
}

// ---------------- metric = mean over heads of K ----------------
__global__ void metric_k(const ushortT* __restrict__ Kb, float* __restrict__ out) {
  int idx = blockIdx.x * blockDim.x + threadIdx.x;   // t*8 + c8
  int t = idx >> 3, c8 = idx & 7;
  float acc[8] = {};
#pragma unroll
  for (int h = 0; h < HEADS; ++h) {
    short8 v = *(const short8*)(Kb + ((size_t)h * L_SEQ + t) * HD + c8 * 8);
#pragma unroll
    for (int j = 0; j < 8; ++j) acc[j] += bf2f((ushortT)v[j]);
  }
  float* dst = out + (size_t)t * HD + c8 * 8;
#pragma unroll
  for (int j = 0; j < 8; ++j) dst[j] = acc[j] * (1.0f / 16.0f);
}

extern "C" void kernel_launch(void* const* d_in, const int* in_sizes, int n_in,
                              void* d_out, int out_size, void* d_ws, size_t ws_size,
                              hipStream_t stream) {
  const float* hs = (const float*)d_in[0];
  const float* sz = (const float*)d_in[1];
  const float* wq = (const float*)d_in[2];
  const float* bq = (const float*)d_in[3];
  const float* wk = (const float*)d_in[4];
  const float* bk = (const float*)d_in[5];
  const float* wv = (const float*)d_in[6];
  const float* bv = (const float*)d_in[7];
  const float* wo = (const float*)d_in[8];
  const float* bo = (const float*)d_in[9];

  char* ws = (char*)d_ws;
  ushortT* hs_b = (ushortT*)(ws);                 // [4096][1024] bf16
  ushortT* wq_b = (ushortT*)(ws + (8u << 20));    // 4 weights bf16 (contiguous)
  ushortT* wk_b = wq_b + (1u << 20);
  ushortT* wv_b = wq_b + (2u << 20);
  ushortT* wo_b = wq_b + (3u << 20);
  ushortT* q_b  = (ushortT*)(ws + (16u << 20));   // [16][4096][64]
  ushortT* k_b  = (ushortT*)(ws + (24u << 20));   // [16][4096][64]
  ushortT* vt_b = (ushortT*)(ws + (32u << 20));   // [16][64][4096]
  ushortT* at_b = (ushortT*)(ws + (40u << 20));   // [4096][1024]
  float*   l2s  = (float*)(ws + (48u << 20));     // [4096]

  float* outp    = (float*)d_out;
  float* metricp = outp + (size_t)L_SEQ * EMBED;

  cast_bf16_k<<<L_SEQ * EMBED / 8 / 256, 256, 0, stream>>>(hs, hs_b, L_SEQ * EMBED / 8);
  cast4_bf16_k<<<2048, 256, 0, stream>>>(wq, wk, wv, wo, wq_b);
  l2size_k<<<L_SEQ / 256, 256, 0, stream>>>(sz, l2s, L_SEQ);

  GemmArgs aq{wq_b, bq, (void*)q_b, 0};
  GemmArgs ak{wk_b, bk, (void*)k_b, 1};
  GemmArgs av{wv_b, bv, (void*)vt_b, 2};
  gemm_bt_k<<<dim3(256, 3), 256, 0, stream>>>(hs_b, aq, ak, av);   // fused QKV

  metric_k<<<L_SEQ * 8 / 256, 256, 0, stream>>>(k_b, metricp);

  attn_k<<<512, 512, 0, stream>>>(q_b, k_b, vt_b, l2s, at_b);

  gemm_o64_k<<<512, 256, 0, stream>>>(at_b, wo_b, bo, outp);       // O projection
}

// Round 22
// 171.875 us; speedup vs baseline: 1.4697x; 1.0419x over previous
//
#include <hip/hip_runtime.h>

// Problem: B=1, L=4096, EMBED=1024, 16 heads x 64
static constexpr int L_SEQ = 4096;
static constexpr int EMBED = 1024;
static constexpr int HEADS = 16;
static constexpr int HD    = 64;

typedef unsigned short ushortT;
typedef __attribute__((ext_vector_type(8)))  short short8;   // 8 x bf16 (4 VGPR)
typedef __attribute__((ext_vector_type(4)))  float f32x4;
typedef __attribute__((ext_vector_type(4)))  unsigned uint4v;

#define LOG2E 1.4426950408889634f

__device__ __forceinline__ ushortT f2bf(float f) {
  unsigned u = __builtin_bit_cast(unsigned, f);
  u += 0x7fffu + ((u >> 16) & 1u);          // round-to-nearest-even
  return (ushortT)(u >> 16);
}
__device__ __forceinline__ float bf2f(ushortT s) {
  return __builtin_bit_cast(float, ((unsigned)s) << 16);
}
// v_cvt_pk_bf16_f32: two f32 -> u32 of 2x bf16 (lo=a, hi=b), RNE on CDNA4
__device__ __forceinline__ unsigned cvtpk(float a, float b) {
  unsigned r;
  asm("v_cvt_pk_bf16_f32 %0, %1, %2" : "=v"(r) : "v"(a), "v"(b));
  return r;
}

// async global->LDS, 16B/lane; LDS dest is wave-uniform base + lane*16.
#define GLOAD_LDS16(g, l) \
  __builtin_amdgcn_global_load_lds((const __attribute__((address_space(1))) void*)(g), \
                                   (__attribute__((address_space(3))) void*)(l), 16, 0, 0)

// ---------------- fused prep: hs cast | 4-weight cast | log2(size) ----------
// blocks [0,2048): hs 4M elems; [2048,4096): weights 4x1M; [4096,4112): l2s.
__global__ void prep_k(const float* __restrict__ hs,
                       const float* __restrict__ wq, const float* __restrict__ wk,
                       const float* __restrict__ wv, const float* __restrict__ wo,
                       const float* __restrict__ sz,
                       ushortT* __restrict__ hs_b, ushortT* __restrict__ w_b,
                       float* __restrict__ l2s) {
  const int b = blockIdx.x, tid = threadIdx.x;
  if (b < 2048) {                    // hs: 524288 x 8 elems
    int i = b * 256 + tid;
    const float4* p = (const float4*)hs;
    float4 a = p[2 * i], c = p[2 * i + 1];
    uint4 o;
    o.x = (unsigned)f2bf(a.x) | ((unsigned)f2bf(a.y) << 16);
    o.y = (unsigned)f2bf(a.z) | ((unsigned)f2bf(a.w) << 16);
    o.z = (unsigned)f2bf(c.x) | ((unsigned)f2bf(c.y) << 16);
    o.w = (unsigned)f2bf(c.z) | ((unsigned)f2bf(c.w) << 16);
    ((uint4*)hs_b)[i] = o;
  } else if (b < 4096) {             // weights: 4 x 131072 x 8 elems
    int idx = (b - 2048) * 256 + tid;
    int w = idx >> 17, i = idx & 131071;
    const float* src = (w == 0) ? wq : (w == 1) ? wk : (w == 2) ? wv : wo;
    const float4* p = (const float4*)src;
    float4 x = p[2 * i], y = p[2 * i + 1];
    uint4 o;
    o.x = (unsigned)f2bf(x.x) | ((unsigned)f2bf(x.y) << 16);
    o.y = (unsigned)f2bf(x.z) | ((unsigned)f2bf(x.w) << 16);
    o.z = (unsigned)f2bf(y.x) | ((unsigned)f2bf(y.y) << 16);
    o.w = (unsigned)f2bf(y.z) | ((unsigned)f2bf(y.w) << 16);
    ((uint4*)(w_b + ((size_t)w << 20)))[i] = o;
  } else {                           // l2s: 4096 elems
    int i = (b - 4096) * 256 + tid;
    if (i < L_SEQ) l2s[i] = __log2f(sz[i]);
  }
}

// ---------------- GEMM: C[M,N] = A[M,K] @ B[N,K]^T + bias ----------------
struct GemmArgs { const ushortT* B; const float* bias; void* dst; int mode; };
// mode 0: Q -> bf16 [h][t][64] * (0.125*LOG2E)   mode 1: K -> bf16 [h][t][64]
// mode 2: V -> bf16 [h][64][t] (transposed)

__global__ __launch_bounds__(256, 3) void gemm_bt_k(
    const ushortT* __restrict__ A, GemmArgs g0, GemmArgs g1, GemmArgs g2)
{
  constexpr int K = 1024;
  __shared__ __align__(16) ushortT As[128 * 64];
  __shared__ __align__(16) ushortT Bs[128 * 64];

  GemmArgs g = (blockIdx.y == 0) ? g0 : ((blockIdx.y == 1) ? g1 : g2);
  const ushortT* __restrict__ Bw = g.B;

  const int tid = threadIdx.x;
  const int wv = tid >> 6, ln = tid & 63;
  // XCD-locality decode (T1): nb = id&7 so each XCD serves ONE 128-col B-panel
  const int nb = blockIdx.x & 7, mb = blockIdx.x >> 3;      // 8 x 32 blocks
  const int m0 = mb * 128, n0 = nb * 128;
  const int wr = wv >> 1, wc = wv & 1;
  const int lrow = ln & 15, lq = ln >> 4;

  const int rstg = wv * 8 + (ln >> 3);
  const int ustg = (ln & 7) ^ (ln >> 3);

  f32x4 acc[4][4] = {};

  for (int kt = 0; kt < K; kt += 64) {
#pragma unroll
    for (int i = 0; i < 4; ++i) {
      int r = i * 32 + rstg;
      GLOAD_LDS16(A  + (size_t)(m0 + r) * K + kt + (ustg << 3), As + i * 2048 + wv * 512);
      GLOAD_LDS16(Bw + (size_t)(n0 + r) * K + kt + (ustg << 3), Bs + i * 2048 + wv * 512);
    }
    __syncthreads();
#pragma unroll
    for (int ks = 0; ks < 2; ++ks) {
      short8 a[4], b[4];
#pragma unroll
      for (int mi = 0; mi < 4; ++mi) {
        int ra = wr * 64 + mi * 16 + lrow;
        int u = (ks * 4 + lq) ^ (ra & 7);
        a[mi] = *(const short8*)(As + ra * 64 + (u << 3));
      }
#pragma unroll
      for (int ni = 0; ni < 4; ++ni) {
        int rb = wc * 64 + ni * 16 + lrow;
        int u = (ks * 4 + lq) ^ (rb & 7);
        b[ni] = *(const short8*)(Bs + rb * 64 + (u << 3));
      }
#pragma unroll
      for (int mi = 0; mi < 4; ++mi)
#pragma unroll
        for (int ni = 0; ni < 4; ++ni)
          acc[mi][ni] = __builtin_amdgcn_mfma_f32_16x16x32_bf16(a[mi], b[ni], acc[mi][ni], 0, 0, 0);
    }
    __syncthreads();
  }

  const int mode = g.mode;
  if (mode <= 1) {
    ushortT* dst = (ushortT*)g.dst;
    const float sc = (mode == 0) ? (0.125f * LOG2E) : 1.0f;
#pragma unroll
    for (int ni = 0; ni < 4; ++ni) {
      int n = n0 + wc * 64 + ni * 16 + lrow;
      float bsv = g.bias[n];
      size_t base = ((size_t)(n >> 6) * L_SEQ) * HD + (n & 63);
#pragma unroll
      for (int mi = 0; mi < 4; ++mi)
#pragma unroll
        for (int r = 0; r < 4; ++r) {
          int m = m0 + wr * 64 + mi * 16 + lq * 4 + r;
          dst[base + (size_t)m * HD] = f2bf((acc[mi][ni][r] + bsv) * sc);
        }
    }
  } else {
    ushortT* dst = (ushortT*)g.dst;
#pragma unroll
    for (int ni = 0; ni < 4; ++ni) {
      int n = n0 + wc * 64 + ni * 16 + lrow;     // n == h*64+hd
      float bsv = g.bias[n];
      size_t base = (size_t)n * L_SEQ;
#pragma unroll
      for (int mi = 0; mi < 4; ++mi)
#pragma unroll
        for (int r = 0; r < 4; ++r) {
          int m = m0 + wr * 64 + mi * 16 + lq * 4 + r;
          dst[base + m] = f2bf(acc[mi][ni][r] + bsv);
        }
    }
  }
}

// ---------------- O-projection GEMM: 64x128 tile, fp32 out, 2 blocks/CU -----
__global__ __launch_bounds__(256, 2) void gemm_o64_k(
    const ushortT* __restrict__ A, const ushortT* __restrict__ Bw,
    const float* __restrict__ bias, float* __restrict__ dst)
{
  constexpr int K = 1024;
  __shared__ __align__(16) ushortT As[64 * 64];
  __shared__ __align__(16) ushortT Bs[128 * 64];

  const int tid = threadIdx.x;
  const int wv = tid >> 6, ln = tid & 63;
  const int nb = blockIdx.x & 7, mb = blockIdx.x >> 3;      // 8 x 64 blocks
  const int m0 = mb * 64, n0 = nb * 128;
  const int wr = wv >> 1, wc = wv & 1;
  const int lrow = ln & 15, lq = ln >> 4;

  const int rstg = wv * 8 + (ln >> 3);
  const int ustg = (ln & 7) ^ (ln >> 3);

  f32x4 acc[2][4] = {};

  for (int kt = 0; kt < K; kt += 64) {
#pragma unroll
    for (int i = 0; i < 2; ++i) {
      int r = i * 32 + rstg;
      GLOAD_LDS16(A + (size_t)(m0 + r) * K + kt + (ustg << 3), As + i * 2048 + wv * 512);
    }
#pragma unroll
    for (int i = 0; i < 4; ++i) {
      int r = i * 32 + rstg;
      GLOAD_LDS16(Bw + (size_t)(n0 + r) * K + kt + (ustg << 3), Bs + i * 2048 + wv * 512);
    }
    __syncthreads();
#pragma unroll
    for (int ks = 0; ks < 2; ++ks) {
      short8 a[2], b[4];
#pragma unroll
      for (int mi = 0; mi < 2; ++mi) {
        int ra = wr * 32 + mi * 16 + lrow;
        int u = (ks * 4 + lq) ^ (ra & 7);
        a[mi] = *(const short8*)(As + ra * 64 + (u << 3));
      }
#pragma unroll
      for (int ni = 0; ni < 4; ++ni) {
        int rb = wc * 64 + ni * 16 + lrow;
        int u = (ks * 4 + lq) ^ (rb & 7);
        b[ni] = *(const short8*)(Bs + rb * 64 + (u << 3));
      }
#pragma unroll
      for (int mi = 0; mi < 2; ++mi)
#pragma unroll
        for (int ni = 0; ni < 4; ++ni)
          acc[mi][ni] = __builtin_amdgcn_mfma_f32_16x16x32_bf16(a[mi], b[ni], acc[mi][ni], 0, 0, 0);
    }
    __syncthreads();
  }

#pragma unroll
  for (int ni = 0; ni < 4; ++ni) {
    int n = n0 + wc * 64 + ni * 16 + lrow;
    float bsv = bias[n];
#pragma unroll
    for (int mi = 0; mi < 2; ++mi)
#pragma unroll
      for (int r = 0; r < 4; ++r) {
        int m = m0 + wr * 32 + mi * 16 + lq * 4 + r;
        dst[(size_t)m * EMBED + n] = acc[mi][ni][r] + bsv;
      }
  }
}

// ---------------- flash attention (swapped 16x16, 32 q/wave, in-block KV-split)
// R20 structure (R21's permlane16 reduce FAILED — shfl_xor restored; permlane
// semantics need on-device verification this loop can't provide). Bias-in-
// accumulator: Q pre-scaled 0.125*LOG2E; S accumulators init'd with l2s bias.
__global__ __launch_bounds__(512, 4) void attn_k(
    const ushortT* __restrict__ Q,   // [16][4096][64], pre-scaled 0.125*LOG2E
    const ushortT* __restrict__ Kb,  // [16][4096][64]
    const ushortT* __restrict__ Vt,  // [16][64][4096]
    const float*   __restrict__ l2s, // [4096] log2(size)
    ushortT* __restrict__ O)         // [4096][1024] bf16
{
  __shared__ __align__(16) ushortT Ks[2][2][64 * 64];   // [grp][buf]
  __shared__ __align__(16) ushortT Vs[2][2][64 * 64];   // [grp][buf]

  const int id = blockIdx.x;                 // 0..511
  const int xcd = id & 7, s = id >> 3;       // s: 0..63
  const int h  = xcd * 2 + (s >> 5);         // head (2 per XCD)
  const int q0 = (s & 31) * 128;             // q-tile base (128 rows/block)

  const int tid = threadIdx.x;
  const int wv  = tid >> 6;                  // 0..7
  const int grp = wv >> 2, wvg = wv & 3;     // KV-half group, wave-in-group
  const int ln  = tid & 63;
  const int lrow = ln & 15, lq = ln >> 4;

  // Q fragments for two q-halves: hf covers q = q0 + wvg*32 + hf*16 + lrow
  short8 qf[2][2];                 // [half][ks]
#pragma unroll
  for (int hf = 0; hf < 2; ++hf) {
    const ushortT* qp = Q + ((size_t)h * L_SEQ + q0 + wvg * 32 + hf * 16 + lrow) * HD + lq * 8;
    qf[hf][0] = *(const short8*)qp;
    qf[hf][1] = *(const short8*)(qp + 32);
  }

  f32x4 o0[4] = {}, o1[4] = {};     // O^T per half: o[df][r] = O[16df+4lq+r][q]
  float mrun0 = -1e30f, lrun0 = 0.f;
  float mrun1 = -1e30f, lrun1 = 0.f;

  const int rstg = wvg * 8 + (ln >> 3);
  const int ustg = (ln & 7) ^ (ln >> 3);

  const ushortT* kbase = Kb + ((size_t)h * L_SEQ + rstg) * HD + (ustg << 3);
  const ushortT* vbase = Vt + ((size_t)(h * HD) + rstg) * L_SEQ + (ustg << 3);

  auto STAGE = [&](int buf, int kt) {        // kt = global tile index
    const int t0 = kt * 64;
#pragma unroll
    for (int i = 0; i < 2; ++i) {
      GLOAD_LDS16(kbase + t0 * 64 + i * (32 * HD), &Ks[grp][buf][i * 2048 + wvg * 512]);
      GLOAD_LDS16(vbase + t0 + i * (32 * L_SEQ),   &Vs[grp][buf][i * 2048 + wvg * 512]);
    }
  };

  // loop-invariant V-read byte offsets (key groups {4lq,16+4lq,32+4lq,48+4lq},
  // slot = natural ^ (lrow&7); d = 16df+lrow so d&7 == lrow&7, df-invariant)
  const int sw = lrow & 7;
  const int vo0 = lrow * 128 + ((((lq >> 1))     ^ sw) << 4) + (lq & 1) * 8;
  const int vo1 = lrow * 128 + ((((lq >> 1) + 2) ^ sw) << 4) + (lq & 1) * 8;
  const int vo2 = lrow * 128 + ((((lq >> 1) + 4) ^ sw) << 4) + (lq & 1) * 8;
  const int vo3 = lrow * 128 + ((((lq >> 1) + 6) ^ sw) << 4) + (lq & 1) * 8;

  const int tbase = grp * 32;        // this group's KV tile range
  STAGE(0, tbase);
  __syncthreads();                   // tile 0 resident (both groups)

#pragma unroll 1
  for (int t = 0; t < 32; ++t) {
    const int cur = t & 1;
    if (t + 1 < 32) STAGE(cur ^ 1, tbase + t + 1);  // overlaps entire compute
    const int t0 = (tbase + t) * 64;
    const ushortT* Kt = &Ks[grp][cur][0];
    const char*    Vb = (const char*)&Vs[grp][cur][0];

    // S^T accumulators initialized with bias (key of s[f][r] = t0+16f+4lq+r);
    // Q carries the LOG2E scale, so MFMA output = S*log2e + bias directly.
    f32x4 s0[4], s1[4];
#pragma unroll
    for (int f = 0; f < 4; ++f) {
      f32x4 b = *(const f32x4*)(l2s + t0 + f * 16 + lq * 4);
      s0[f] = b; s1[f] = b;
    }

    __builtin_amdgcn_s_setprio(1);
#pragma unroll
    for (int ks = 0; ks < 2; ++ks) {
#pragma unroll
      for (int f = 0; f < 4; ++f) {
        int key = f * 16 + lrow;
        int u = (ks * 4 + lq) ^ (key & 7);
        short8 kb = *(const short8*)(Kt + key * 64 + (u << 3));
        s0[f] = __builtin_amdgcn_mfma_f32_16x16x32_bf16(kb, qf[0][ks], s0[f], 0, 0, 0);
        s1[f] = __builtin_amdgcn_mfma_f32_16x16x32_bf16(kb, qf[1][ks], s1[f], 0, 0, 0);
      }
    }
    __builtin_amdgcn_s_setprio(0);

    // softmax per half: in-lane tree + 2 cross-lane steps (reduce over lq)
    float pm0 = fmaxf(fmaxf(fmaxf(s0[0][0], s0[0][1]), fmaxf(s0[0][2], s0[0][3])),
                      fmaxf(fmaxf(s0[1][0], s0[1][1]), fmaxf(s0[1][2], s0[1][3])));
    pm0 = fmaxf(pm0, fmaxf(fmaxf(fmaxf(s0[2][0], s0[2][1]), fmaxf(s0[2][2], s0[2][3])),
                           fmaxf(fmaxf(s0[3][0], s0[3][1]), fmaxf(s0[3][2], s0[3][3]))));
    float pm1 = fmaxf(fmaxf(fmaxf(s1[0][0], s1[0][1]), fmaxf(s1[0][2], s1[0][3])),
                      fmaxf(fmaxf(s1[1][0], s1[1][1]), fmaxf(s1[1][2], s1[1][3])));
    pm1 = fmaxf(pm1, fmaxf(fmaxf(fmaxf(s1[2][0], s1[2][1]), fmaxf(s1[2][2], s1[2][3])),
                           fmaxf(fmaxf(s1[3][0], s1[3][1]), fmaxf(s1[3][2], s1[3][3]))));
    pm0 = fmaxf(pm0, __shfl_xor(pm0, 16));
    pm0 = fmaxf(pm0, __shfl_xor(pm0, 32));
    pm1 = fmaxf(pm1, __shfl_xor(pm1, 16));
    pm1 = fmaxf(pm1, __shfl_xor(pm1, 32));
    float mnew0  = fmaxf(mrun0, pm0);
    float mnew1  = fmaxf(mrun1, pm1);
    float alpha0 = __builtin_amdgcn_exp2f(mrun0 - mnew0);
    float alpha1 = __builtin_amdgcn_exp2f(mrun1 - mnew1);
    mrun0 = mnew0; mrun1 = mnew1;

    float rs0 = 0.f, rs1 = 0.f;
#pragma unroll
    for (int f = 0; f < 4; ++f)
#pragma unroll
      for (int r = 0; r < 4; ++r) {
        float pv0 = __builtin_amdgcn_exp2f(s0[f][r] - mrun0);
        float pv1 = __builtin_amdgcn_exp2f(s1[f][r] - mrun1);
        s0[f][r] = pv0; rs0 += pv0;
        s1[f][r] = pv1; rs1 += pv1;
      }
    rs0 += __shfl_xor(rs0, 16);
    rs0 += __shfl_xor(rs0, 32);
    rs1 += __shfl_xor(rs1, 16);
    rs1 += __shfl_xor(rs1, 32);
    lrun0 = lrun0 * alpha0 + rs0;
    lrun1 = lrun1 * alpha1 + rs1;

    if (!__all(alpha0 == 1.0f && alpha1 == 1.0f)) {
#pragma unroll
      for (int df = 0; df < 4; ++df)
#pragma unroll
        for (int r = 0; r < 4; ++r) {
          o0[df][r] *= alpha0;
          o1[df][r] *= alpha1;
        }
    }

    // P -> bf16 B-fragments in-register (kappa ordering), per half
    short8 pb00, pb10, pb01, pb11;   // pb<kgroup><half>
    {
      unsigned a0 = cvtpk(s0[0][0], s0[0][1]), a1 = cvtpk(s0[0][2], s0[0][3]);
      unsigned a2 = cvtpk(s0[1][0], s0[1][1]), a3 = cvtpk(s0[1][2], s0[1][3]);
      unsigned a4 = cvtpk(s0[2][0], s0[2][1]), a5 = cvtpk(s0[2][2], s0[2][3]);
      unsigned a6 = cvtpk(s0[3][0], s0[3][1]), a7 = cvtpk(s0[3][2], s0[3][3]);
      pb00 = __builtin_bit_cast(short8, (uint4v){a0, a1, a2, a3});  // keys 0..31
      pb10 = __builtin_bit_cast(short8, (uint4v){a4, a5, a6, a7});  // keys 32..63
      unsigned b0 = cvtpk(s1[0][0], s1[0][1]), b1 = cvtpk(s1[0][2], s1[0][3]);
      unsigned b2 = cvtpk(s1[1][0], s1[1][1]), b3 = cvtpk(s1[1][2], s1[1][3]);
      unsigned b4 = cvtpk(s1[2][0], s1[2][1]), b5 = cvtpk(s1[2][2], s1[2][3]);
      unsigned b6 = cvtpk(s1[3][0], s1[3][1]), b7 = cvtpk(s1[3][2], s1[3][3]);
      pb01 = __builtin_bit_cast(short8, (uint4v){b0, b1, b2, b3});
      pb11 = __builtin_bit_cast(short8, (uint4v){b4, b5, b6, b7});
    }

    // O^T += V P : each V-fragment read feeds 2 MFMAs (both q-halves)
    __builtin_amdgcn_s_setprio(1);
#pragma unroll
    for (int df = 0; df < 4; ++df) {
      const char* vr = Vb + df * 2048;
      uint2 a0 = *(const uint2*)(vr + vo0);
      uint2 a1 = *(const uint2*)(vr + vo1);
      short8 va = __builtin_bit_cast(short8, (uint4v){a0.x, a0.y, a1.x, a1.y});
      o0[df] = __builtin_amdgcn_mfma_f32_16x16x32_bf16(va, pb00, o0[df], 0, 0, 0);
      o1[df] = __builtin_amdgcn_mfma_f32_16x16x32_bf16(va, pb01, o1[df], 0, 0, 0);
      uint2 a2 = *(const uint2*)(vr + vo2);
      uint2 a3 = *(const uint2*)(vr + vo3);
      short8 vb2 = __builtin_bit_cast(short8, (uint4v){a2.x, a2.y, a3.x, a3.y});
      o0[df] = __builtin_amdgcn_mfma_f32_16x16x32_bf16(vb2, pb10, o0[df], 0, 0, 0);
      o1[df] = __builtin_amdgcn_mfma_f32_16x16x32_bf16(vb2, pb11, o1[df], 0, 0, 0);
    }
    __builtin_amdgcn_s_setprio(0);

    __syncthreads();                 // drains next-tile loads; frees cur buffer
  }

  // ---- combine: group 1 publishes partials via the dead K/V LDS buffers ----
  float* Ob = (float*)&Ks[0][0][0];  // [128 q][64 d] fp32 = 32 KB
  float* Ml = (float*)&Vs[0][0][0];  // [128 q][2] (m, l)
  const int ql0 = wvg * 32 + lrow;   // q_local of half 0; half 1 = +16

  if (grp == 1) {
#pragma unroll
    for (int df = 0; df < 4; ++df) {
      *(f32x4*)(Ob + ql0 * 64 + df * 16 + lq * 4)        = o0[df];
      *(f32x4*)(Ob + (ql0 + 16) * 64 + df * 16 + lq * 4) = o1[df];
    }
    Ml[ql0 * 2] = mrun0;        Ml[ql0 * 2 + 1] = lrun0;
    Ml[(ql0 + 16) * 2] = mrun1; Ml[(ql0 + 16) * 2 + 1] = lrun1;
  }
  __syncthreads();
  if (grp == 0) {
    // merge half 0
    {
      float m1 = Ml[ql0 * 2], l1 = Ml[ql0 * 2 + 1];
      float m  = fmaxf(mrun0, m1);
      float w0 = __builtin_amdgcn_exp2f(mrun0 - m);
      float w1 = __builtin_amdgcn_exp2f(m1 - m);
      float inv = 1.0f / (lrun0 * w0 + l1 * w1);
      ushortT* ob = O + (size_t)(q0 + ql0) * EMBED + h * HD;
#pragma unroll
      for (int df = 0; df < 4; ++df) {
        f32x4 p1 = *(const f32x4*)(Ob + ql0 * 64 + df * 16 + lq * 4);
        uint2 w;
        w.x = (unsigned)f2bf((o0[df][0] * w0 + p1[0] * w1) * inv) |
              ((unsigned)f2bf((o0[df][1] * w0 + p1[1] * w1) * inv) << 16);
        w.y = (unsigned)f2bf((o0[df][2] * w0 + p1[2] * w1) * inv) |
              ((unsigned)f2bf((o0[df][3] * w0 + p1[3] * w1) * inv) << 16);
        *(uint2*)(ob + df * 16 + lq * 4) = w;
      }
    }
    // merge half 1
    {
      float m1 = Ml[(ql0 + 16) * 2], l1 = Ml[(ql0 + 16) * 2 + 1];
      float m  = fmaxf(mrun1, m1);
      float w0 = __builtin_amdgcn_exp2f(mrun1 - m);
      float w1 = __builtin_amdgcn_exp2f(m1 - m);
      float inv = 1.0f / (lrun1 * w0 + l1 * w1);
      ushortT* ob = O + (size_t)(q0 + ql0 + 16) * EMBED + h * HD;
#pragma unroll
      for (int df = 0; df < 4; ++df) {
        f32x4 p1 = *(const f32x4*)(Ob + (ql0 + 16) * 64 + df * 16 + lq * 4);
        uint2 w;
        w.x = (unsigned)f2bf((o1[df][0] * w0 + p1[0] * w1) * inv) |
              ((unsigned)f2bf((o1[df][1] * w0 + p1[1] * w1) * inv) << 16);
        w.y = (unsigned)f2bf((o1[df][2] * w0 + p1[2] * w1) * inv) |
              ((unsigned)f2bf((o1[df][3] * w0 + p1[3] * w1) * inv) << 16);
        *(uint2*)(ob + df * 16 + lq * 4) = w;
      }
    }
  }
}

// ---------------- metric = mean over heads of K ----------------
__global__ void metric_k(const ushortT* __restrict__ Kb, float* __restrict__ out) {
  int idx = blockIdx.x * blockDim.x + threadIdx.x;   // t*8 + c8
  int t = idx >> 3, c8 = idx & 7;
  float acc[8] = {};
#pragma unroll
  for (int h = 0; h < HEADS; ++h) {
    short8 v = *(const short8*)(Kb + ((size_t)h * L_SEQ + t) * HD + c8 * 8);
#pragma unroll
    for (int j = 0; j < 8; ++j) acc[j] += bf2f((ushortT)v[j]);
  }
  float* dst = out + (size_t)t * HD + c8 * 8;
#pragma unroll
  for (int j = 0; j < 8; ++j) dst[j] = acc[j] * (1.0f / 16.0f);
}

extern "C" void kernel_launch(void* const* d_in, const int* in_sizes, int n_in,
                              void* d_out, int out_size, void* d_ws, size_t ws_size,
                              hipStream_t stream) {
  const float* hs = (const float*)d_in[0];
  const float* sz = (const float*)d_in[1];
  const float* wq = (const float*)d_in[2];
  const float* bq = (const float*)d_in[3];
  const float* wk = (const float*)d_in[4];
  const float* bk = (const float*)d_in[5];
  const float* wv = (const float*)d_in[6];
  const float* bv = (const float*)d_in[7];
  const float* wo = (const float*)d_in[8];
  const float* bo = (const float*)d_in[9];

  char* ws = (char*)d_ws;
  ushortT* hs_b = (ushortT*)(ws);                 // [4096][1024] bf16
  ushortT* wq_b = (ushortT*)(ws + (8u << 20));    // 4 weights bf16 (contiguous)
  ushortT* wk_b = wq_b + (1u << 20);
  ushortT* wv_b = wq_b + (2u << 20);
  ushortT* wo_b = wq_b + (3u << 20);
  ushortT* q_b  = (ushortT*)(ws + (16u << 20));   // [16][4096][64]
  ushortT* k_b  = (ushortT*)(ws + (24u << 20));   // [16][4096][64]
  ushortT* vt_b = (ushortT*)(ws + (32u << 20));   // [16][64][4096]
  ushortT* at_b = (ushortT*)(ws + (40u << 20));   // [4096][1024]
  float*   l2s  = (float*)(ws + (48u << 20));     // [4096]

  float* outp    = (float*)d_out;
  float* metricp = outp + (size_t)L_SEQ * EMBED;

  prep_k<<<4112, 256, 0, stream>>>(hs, wq, wk, wv, wo, sz, hs_b, wq_b, l2s);

  GemmArgs aq{wq_b, bq, (void*)q_b, 0};
  GemmArgs ak{wk_b, bk, (void*)k_b, 1};
  GemmArgs av{wv_b, bv, (void*)vt_b, 2};
  gemm_bt_k<<<dim3(256, 3), 256, 0, stream>>>(hs_b, aq, ak, av);   // fused QKV

  metric_k<<<L_SEQ * 8 / 256, 256, 0, stream>>>(k_b, metricp);

  attn_k<<<512, 512, 0, stream>>>(q_b, k_b, vt_b, l2s, at_b);

  gemm_o64_k<<<512, 256, 0, stream>>>(at_b, wo_b, bo, outp);       // O projection
}

// Round 23
// 170.235 us; speedup vs baseline: 1.4839x; 1.0096x over previous
//
#include <hip/hip_runtime.h>

// Problem: B=1, L=4096, EMBED=1024, 16 heads x 64
static constexpr int L_SEQ = 4096;
static constexpr int EMBED = 1024;
static constexpr int HEADS = 16;
static constexpr int HD    = 64;

typedef unsigned short ushortT;
typedef __attribute__((ext_vector_type(8)))  short short8;   // 8 x bf16 (4 VGPR)
typedef __attribute__((ext_vector_type(4)))  float f32x4;
typedef __attribute__((ext_vector_type(4)))  unsigned uint4v;

#define LOG2E 1.4426950408889634f

__device__ __forceinline__ ushortT f2bf(float f) {
  unsigned u = __builtin_bit_cast(unsigned, f);
  u += 0x7fffu + ((u >> 16) & 1u);          // round-to-nearest-even
  return (ushortT)(u >> 16);
}
__device__ __forceinline__ float bf2f(ushortT s) {
  return __builtin_bit_cast(float, ((unsigned)s) << 16);
}
// v_cvt_pk_bf16_f32: two f32 -> u32 of 2x bf16 (lo=a, hi=b), RNE on CDNA4
__device__ __forceinline__ unsigned cvtpk(float a, float b) {
  unsigned r;
  asm("v_cvt_pk_bf16_f32 %0, %1, %2" : "=v"(r) : "v"(a), "v"(b));
  return r;
}
// chained max over 16 values; fmaxf(fmaxf(m,x),y) fuses to v_max3_f32
__device__ __forceinline__ float max16c(const f32x4* s) {
  float m = fmaxf(fmaxf(s[0][0], s[0][1]), s[0][2]);
  m = fmaxf(fmaxf(m, s[0][3]), s[1][0]);
  m = fmaxf(fmaxf(m, s[1][1]), s[1][2]);
  m = fmaxf(fmaxf(m, s[1][3]), s[2][0]);
  m = fmaxf(fmaxf(m, s[2][1]), s[2][2]);
  m = fmaxf(fmaxf(m, s[2][3]), s[3][0]);
  m = fmaxf(fmaxf(m, s[3][1]), s[3][2]);
  m = fmaxf(m, s[3][3]);
  return m;
}

// async global->LDS, 16B/lane; LDS dest is wave-uniform base + lane*16.
#define GLOAD_LDS16(g, l) \
  __builtin_amdgcn_global_load_lds((const __attribute__((address_space(1))) void*)(g), \
                                   (__attribute__((address_space(3))) void*)(l), 16, 0, 0)

// ---------------- fused prep: hs cast | 4-weight cast | log2(size) ----------
// blocks [0,2048): hs 4M elems; [2048,4096): weights 4x1M; [4096,4112): l2s.
__global__ void prep_k(const float* __restrict__ hs,
                       const float* __restrict__ wq, const float* __restrict__ wk,
                       const float* __restrict__ wv, const float* __restrict__ wo,
                       const float* __restrict__ sz,
                       ushortT* __restrict__ hs_b, ushortT* __restrict__ w_b,
                       float* __restrict__ l2s) {
  const int b = blockIdx.x, tid = threadIdx.x;
  if (b < 2048) {                    // hs: 524288 x 8 elems
    int i = b * 256 + tid;
    const float4* p = (const float4*)hs;
    float4 a = p[2 * i], c = p[2 * i + 1];
    uint4 o;
    o.x = (unsigned)f2bf(a.x) | ((unsigned)f2bf(a.y) << 16);
    o.y = (unsigned)f2bf(a.z) | ((unsigned)f2bf(a.w) << 16);
    o.z = (unsigned)f2bf(c.x) | ((unsigned)f2bf(c.y) << 16);
    o.w = (unsigned)f2bf(c.z) | ((unsigned)f2bf(c.w) << 16);
    ((uint4*)hs_b)[i] = o;
  } else if (b < 4096) {             // weights: 4 x 131072 x 8 elems
    int idx = (b - 2048) * 256 + tid;
    int w = idx >> 17, i = idx & 131071;
    const float* src = (w == 0) ? wq : (w == 1) ? wk : (w == 2) ? wv : wo;
    const float4* p = (const float4*)src;
    float4 x = p[2 * i], y = p[2 * i + 1];
    uint4 o;
    o.x = (unsigned)f2bf(x.x) | ((unsigned)f2bf(x.y) << 16);
    o.y = (unsigned)f2bf(x.z) | ((unsigned)f2bf(x.w) << 16);
    o.z = (unsigned)f2bf(y.x) | ((unsigned)f2bf(y.y) << 16);
    o.w = (unsigned)f2bf(y.z) | ((unsigned)f2bf(y.w) << 16);
    ((uint4*)(w_b + ((size_t)w << 20)))[i] = o;
  } else {                           // l2s: 4096 elems
    int i = (b - 4096) * 256 + tid;
    if (i < L_SEQ) l2s[i] = __log2f(sz[i]);
  }
}

// ---------------- GEMM: C[M,N] = A[M,K] @ B[N,K]^T + bias ----------------
struct GemmArgs { const ushortT* B; const float* bias; void* dst; int mode; };
// mode 0: Q -> bf16 [h][t][64] * (0.125*LOG2E)   mode 1: K -> bf16 [h][t][64]
// mode 2: V -> bf16 [h][64][t] (transposed)

__global__ __launch_bounds__(256, 3) void gemm_bt_k(
    const ushortT* __restrict__ A, GemmArgs g0, GemmArgs g1, GemmArgs g2)
{
  constexpr int K = 1024;
  __shared__ __align__(16) ushortT As[128 * 64];
  __shared__ __align__(16) ushortT Bs[128 * 64];

  GemmArgs g = (blockIdx.y == 0) ? g0 : ((blockIdx.y == 1) ? g1 : g2);
  const ushortT* __restrict__ Bw = g.B;

  const int tid = threadIdx.x;
  const int wv = tid >> 6, ln = tid & 63;
  // XCD-locality decode (T1): nb = id&7 so each XCD serves ONE 128-col B-panel
  const int nb = blockIdx.x & 7, mb = blockIdx.x >> 3;      // 8 x 32 blocks
  const int m0 = mb * 128, n0 = nb * 128;
  const int wr = wv >> 1, wc = wv & 1;
  const int lrow = ln & 15, lq = ln >> 4;

  const int rstg = wv * 8 + (ln >> 3);
  const int ustg = (ln & 7) ^ (ln >> 3);

  f32x4 acc[4][4] = {};

  for (int kt = 0; kt < K; kt += 64) {
#pragma unroll
    for (int i = 0; i < 4; ++i) {
      int r = i * 32 + rstg;
      GLOAD_LDS16(A  + (size_t)(m0 + r) * K + kt + (ustg << 3), As + i * 2048 + wv * 512);
      GLOAD_LDS16(Bw + (size_t)(n0 + r) * K + kt + (ustg << 3), Bs + i * 2048 + wv * 512);
    }
    __syncthreads();
#pragma unroll
    for (int ks = 0; ks < 2; ++ks) {
      short8 a[4], b[4];
#pragma unroll
      for (int mi = 0; mi < 4; ++mi) {
        int ra = wr * 64 + mi * 16 + lrow;
        int u = (ks * 4 + lq) ^ (ra & 7);
        a[mi] = *(const short8*)(As + ra * 64 + (u << 3));
      }
#pragma unroll
      for (int ni = 0; ni < 4; ++ni) {
        int rb = wc * 64 + ni * 16 + lrow;
        int u = (ks * 4 + lq) ^ (rb & 7);
        b[ni] = *(const short8*)(Bs + rb * 64 + (u << 3));
      }
#pragma unroll
      for (int mi = 0; mi < 4; ++mi)
#pragma unroll
        for (int ni = 0; ni < 4; ++ni)
          acc[mi][ni] = __builtin_amdgcn_mfma_f32_16x16x32_bf16(a[mi], b[ni], acc[mi][ni], 0, 0, 0);
    }
    __syncthreads();
  }

  const int mode = g.mode;
  if (mode <= 1) {
    ushortT* dst = (ushortT*)g.dst;
    const float sc = (mode == 0) ? (0.125f * LOG2E) : 1.0f;
#pragma unroll
    for (int ni = 0; ni < 4; ++ni) {
      int n = n0 + wc * 64 + ni * 16 + lrow;
      float bsv = g.bias[n];
      size_t base = ((size_t)(n >> 6) * L_SEQ) * HD + (n & 63);
#pragma unroll
      for (int mi = 0; mi < 4; ++mi)
#pragma unroll
        for (int r = 0; r < 4; ++r) {
          int m = m0 + wr * 64 + mi * 16 + lq * 4 + r;
          dst[base + (size_t)m * HD] = f2bf((acc[mi][ni][r] + bsv) * sc);
        }
    }
  } else {
    ushortT* dst = (ushortT*)g.dst;
#pragma unroll
    for (int ni = 0; ni < 4; ++ni) {
      int n = n0 + wc * 64 + ni * 16 + lrow;     // n == h*64+hd
      float bsv = g.bias[n];
      size_t base = (size_t)n * L_SEQ;
#pragma unroll
      for (int mi = 0; mi < 4; ++mi)
#pragma unroll
        for (int r = 0; r < 4; ++r) {
          int m = m0 + wr * 64 + mi * 16 + lq * 4 + r;
          dst[base + m] = f2bf(acc[mi][ni][r] + bsv);
        }
    }
  }
}

// ---------------- O-projection GEMM: 64x128 tile, fp32 out, 2 blocks/CU -----
__global__ __launch_bounds__(256, 2) void gemm_o64_k(
    const ushortT* __restrict__ A, const ushortT* __restrict__ Bw,
    const float* __restrict__ bias, float* __restrict__ dst)
{
  constexpr int K = 1024;
  __shared__ __align__(16) ushortT As[64 * 64];
  __shared__ __align__(16) ushortT Bs[128 * 64];

  const int tid = threadIdx.x;
  const int wv = tid >> 6, ln = tid & 63;
  const int nb = blockIdx.x & 7, mb = blockIdx.x >> 3;      // 8 x 64 blocks
  const int m0 = mb * 64, n0 = nb * 128;
  const int wr = wv >> 1, wc = wv & 1;
  const int lrow = ln & 15, lq = ln >> 4;

  const int rstg = wv * 8 + (ln >> 3);
  const int ustg = (ln & 7) ^ (ln >> 3);

  f32x4 acc[2][4] = {};

  for (int kt = 0; kt < K; kt += 64) {
#pragma unroll
    for (int i = 0; i < 2; ++i) {
      int r = i * 32 + rstg;
      GLOAD_LDS16(A + (size_t)(m0 + r) * K + kt + (ustg << 3), As + i * 2048 + wv * 512);
    }
#pragma unroll
    for (int i = 0; i < 4; ++i) {
      int r = i * 32 + rstg;
      GLOAD_LDS16(Bw + (size_t)(n0 + r) * K + kt + (ustg << 3), Bs + i * 2048 + wv * 512);
    }
    __syncthreads();
#pragma unroll
    for (int ks = 0; ks < 2; ++ks) {
      short8 a[2], b[4];
#pragma unroll
      for (int mi = 0; mi < 2; ++mi) {
        int ra = wr * 32 + mi * 16 + lrow;
        int u = (ks * 4 + lq) ^ (ra & 7);
        a[mi] = *(const short8*)(As + ra * 64 + (u << 3));
      }
#pragma unroll
      for (int ni = 0; ni < 4; ++ni) {
        int rb = wc * 64 + ni * 16 + lrow;
        int u = (ks * 4 + lq) ^ (rb & 7);
        b[ni] = *(const short8*)(Bs + rb * 64 + (u << 3));
      }
#pragma unroll
      for (int mi = 0; mi < 2; ++mi)
#pragma unroll
        for (int ni = 0; ni < 4; ++ni)
          acc[mi][ni] = __builtin_amdgcn_mfma_f32_16x16x32_bf16(a[mi], b[ni], acc[mi][ni], 0, 0, 0);
    }
    __syncthreads();
  }

#pragma unroll
  for (int ni = 0; ni < 4; ++ni) {
    int n = n0 + wc * 64 + ni * 16 + lrow;
    float bsv = bias[n];
#pragma unroll
    for (int mi = 0; mi < 2; ++mi)
#pragma unroll
      for (int r = 0; r < 4; ++r) {
        int m = m0 + wr * 32 + mi * 16 + lq * 4 + r;
        dst[(size_t)m * EMBED + n] = acc[mi][ni][r] + bsv;
      }
  }
}

// ---------------- flash attention (swapped 16x16, 32 q/wave, in-block KV-split)
// R22 structure; R23: in-lane max trees restructured as chained fmaxf for
// v_max3_f32 fusion (max is associative -> bitwise-identical result).
__global__ __launch_bounds__(512, 4) void attn_k(
    const ushortT* __restrict__ Q,   // [16][4096][64], pre-scaled 0.125*LOG2E
    const ushortT* __restrict__ Kb,  // [16][4096][64]
    const ushortT* __restrict__ Vt,  // [16][64][4096]
    const float*   __restrict__ l2s, // [4096] log2(size)
    ushortT* __restrict__ O)         // [4096][1024] bf16
{
  __shared__ __align__(16) ushortT Ks[2][2][64 * 64];   // [grp][buf]
  __shared__ __align__(16) ushortT Vs[2][2][64 * 64];   // [grp][buf]

  const int id = blockIdx.x;                 // 0..511
  const int xcd = id & 7, s = id >> 3;       // s: 0..63
  const int h  = xcd * 2 + (s >> 5);         // head (2 per XCD)
  const int q0 = (s & 31) * 128;             // q-tile base (128 rows/block)

  const int tid = threadIdx.x;
  const int wv  = tid >> 6;                  // 0..7
  const int grp = wv >> 2, wvg = wv & 3;     // KV-half group, wave-in-group
  const int ln  = tid & 63;
  const int lrow = ln & 15, lq = ln >> 4;

  // Q fragments for two q-halves: hf covers q = q0 + wvg*32 + hf*16 + lrow
  short8 qf[2][2];                 // [half][ks]
#pragma unroll
  for (int hf = 0; hf < 2; ++hf) {
    const ushortT* qp = Q + ((size_t)h * L_SEQ + q0 + wvg * 32 + hf * 16 + lrow) * HD + lq * 8;
    qf[hf][0] = *(const short8*)qp;
    qf[hf][1] = *(const short8*)(qp + 32);
  }

  f32x4 o0[4] = {}, o1[4] = {};     // O^T per half: o[df][r] = O[16df+4lq+r][q]
  float mrun0 = -1e30f, lrun0 = 0.f;
  float mrun1 = -1e30f, lrun1 = 0.f;

  const int rstg = wvg * 8 + (ln >> 3);
  const int ustg = (ln & 7) ^ (ln >> 3);

  const ushortT* kbase = Kb + ((size_t)h * L_SEQ + rstg) * HD + (ustg << 3);
  const ushortT* vbase = Vt + ((size_t)(h * HD) + rstg) * L_SEQ + (ustg << 3);

  auto STAGE = [&](int buf, int kt) {        // kt = global tile index
    const int t0 = kt * 64;
#pragma unroll
    for (int i = 0; i < 2; ++i) {
      GLOAD_LDS16(kbase + t0 * 64 + i * (32 * HD), &Ks[grp][buf][i * 2048 + wvg * 512]);
      GLOAD_LDS16(vbase + t0 + i * (32 * L_SEQ),   &Vs[grp][buf][i * 2048 + wvg * 512]);
    }
  };

  // loop-invariant V-read byte offsets (key groups {4lq,16+4lq,32+4lq,48+4lq},
  // slot = natural ^ (lrow&7); d = 16df+lrow so d&7 == lrow&7, df-invariant)
  const int sw = lrow & 7;
  const int vo0 = lrow * 128 + ((((lq >> 1))     ^ sw) << 4) + (lq & 1) * 8;
  const int vo1 = lrow * 128 + ((((lq >> 1) + 2) ^ sw) << 4) + (lq & 1) * 8;
  const int vo2 = lrow * 128 + ((((lq >> 1) + 4) ^ sw) << 4) + (lq & 1) * 8;
  const int vo3 = lrow * 128 + ((((lq >> 1) + 6) ^ sw) << 4) + (lq & 1) * 8;

  const int tbase = grp * 32;        // this group's KV tile range
  STAGE(0, tbase);
  __syncthreads();                   // tile 0 resident (both groups)

#pragma unroll 1
  for (int t = 0; t < 32; ++t) {
    const int cur = t & 1;
    if (t + 1 < 32) STAGE(cur ^ 1, tbase + t + 1);  // overlaps entire compute
    const int t0 = (tbase + t) * 64;
    const ushortT* Kt = &Ks[grp][cur][0];
    const char*    Vb = (const char*)&Vs[grp][cur][0];

    // S^T accumulators initialized with bias (key of s[f][r] = t0+16f+4lq+r);
    // Q carries the LOG2E scale, so MFMA output = S*log2e + bias directly.
    f32x4 s0[4], s1[4];
#pragma unroll
    for (int f = 0; f < 4; ++f) {
      f32x4 b = *(const f32x4*)(l2s + t0 + f * 16 + lq * 4);
      s0[f] = b; s1[f] = b;
    }

    __builtin_amdgcn_s_setprio(1);
#pragma unroll
    for (int ks = 0; ks < 2; ++ks) {
#pragma unroll
      for (int f = 0; f < 4; ++f) {
        int key = f * 16 + lrow;
        int u = (ks * 4 + lq) ^ (key & 7);
        short8 kb = *(const short8*)(Kt + key * 64 + (u << 3));
        s0[f] = __builtin_amdgcn_mfma_f32_16x16x32_bf16(kb, qf[0][ks], s0[f], 0, 0, 0);
        s1[f] = __builtin_amdgcn_mfma_f32_16x16x32_bf16(kb, qf[1][ks], s1[f], 0, 0, 0);
      }
    }
    __builtin_amdgcn_s_setprio(0);

    // softmax per half: chained max (v_max3 fusion) + 2 cross-lane steps
    float pm0 = max16c(s0);
    float pm1 = max16c(s1);
    pm0 = fmaxf(pm0, __shfl_xor(pm0, 16));
    pm0 = fmaxf(pm0, __shfl_xor(pm0, 32));
    pm1 = fmaxf(pm1, __shfl_xor(pm1, 16));
    pm1 = fmaxf(pm1, __shfl_xor(pm1, 32));
    float mnew0  = fmaxf(mrun0, pm0);
    float mnew1  = fmaxf(mrun1, pm1);
    float alpha0 = __builtin_amdgcn_exp2f(mrun0 - mnew0);
    float alpha1 = __builtin_amdgcn_exp2f(mrun1 - mnew1);
    mrun0 = mnew0; mrun1 = mnew1;

    float rs0 = 0.f, rs1 = 0.f;
#pragma unroll
    for (int f = 0; f < 4; ++f)
#pragma unroll
      for (int r = 0; r < 4; ++r) {
        float pv0 = __builtin_amdgcn_exp2f(s0[f][r] - mrun0);
        float pv1 = __builtin_amdgcn_exp2f(s1[f][r] - mrun1);
        s0[f][r] = pv0; rs0 += pv0;
        s1[f][r] = pv1; rs1 += pv1;
      }
    rs0 += __shfl_xor(rs0, 16);
    rs0 += __shfl_xor(rs0, 32);
    rs1 += __shfl_xor(rs1, 16);
    rs1 += __shfl_xor(rs1, 32);
    lrun0 = lrun0 * alpha0 + rs0;
    lrun1 = lrun1 * alpha1 + rs1;

    if (!__all(alpha0 == 1.0f && alpha1 == 1.0f)) {
#pragma unroll
      for (int df = 0; df < 4; ++df)
#pragma unroll
        for (int r = 0; r < 4; ++r) {
          o0[df][r] *= alpha0;
          o1[df][r] *= alpha1;
        }
    }

    // P -> bf16 B-fragments in-register (kappa ordering), per half
    short8 pb00, pb10, pb01, pb11;   // pb<kgroup><half>
    {
      unsigned a0 = cvtpk(s0[0][0], s0[0][1]), a1 = cvtpk(s0[0][2], s0[0][3]);
      unsigned a2 = cvtpk(s0[1][0], s0[1][1]), a3 = cvtpk(s0[1][2], s0[1][3]);
      unsigned a4 = cvtpk(s0[2][0], s0[2][1]), a5 = cvtpk(s0[2][2], s0[2][3]);
      unsigned a6 = cvtpk(s0[3][0], s0[3][1]), a7 = cvtpk(s0[3][2], s0[3][3]);
      pb00 = __builtin_bit_cast(short8, (uint4v){a0, a1, a2, a3});  // keys 0..31
      pb10 = __builtin_bit_cast(short8, (uint4v){a4, a5, a6, a7});  // keys 32..63
      unsigned b0 = cvtpk(s1[0][0], s1[0][1]), b1 = cvtpk(s1[0][2], s1[0][3]);
      unsigned b2 = cvtpk(s1[1][0], s1[1][1]), b3 = cvtpk(s1[1][2], s1[1][3]);
      unsigned b4 = cvtpk(s1[2][0], s1[2][1]), b5 = cvtpk(s1[2][2], s1[2][3]);
      unsigned b6 = cvtpk(s1[3][0], s1[3][1]), b7 = cvtpk(s1[3][2], s1[3][3]);
      pb01 = __builtin_bit_cast(short8, (uint4v){b0, b1, b2, b3});
      pb11 = __builtin_bit_cast(short8, (uint4v){b4, b5, b6, b7});
    }

    // O^T += V P : each V-fragment read feeds 2 MFMAs (both q-halves)
    __builtin_amdgcn_s_setprio(1);
#pragma unroll
    for (int df = 0; df < 4; ++df) {
      const char* vr = Vb + df * 2048;
      uint2 a0 = *(const uint2*)(vr + vo0);
      uint2 a1 = *(const uint2*)(vr + vo1);
      short8 va = __builtin_bit_cast(short8, (uint4v){a0.x, a0.y, a1.x, a1.y});
      o0[df] = __builtin_amdgcn_mfma_f32_16x16x32_bf16(va, pb00, o0[df], 0, 0, 0);
      o1[df] = __builtin_amdgcn_mfma_f32_16x16x32_bf16(va, pb01, o1[df], 0, 0, 0);
      uint2 a2 = *(const uint2*)(vr + vo2);
      uint2 a3 = *(const uint2*)(vr + vo3);
      short8 vb2 = __builtin_bit_cast(short8, (uint4v){a2.x, a2.y, a3.x, a3.y});
      o0[df] = __builtin_amdgcn_mfma_f32_16x16x32_bf16(vb2, pb10, o0[df], 0, 0, 0);
      o1[df] = __builtin_amdgcn_mfma_f32_16x16x32_bf16(vb2, pb11, o1[df], 0, 0, 0);
    }
    __builtin_amdgcn_s_setprio(0);

    __syncthreads();                 // drains next-tile loads; frees cur buffer
  }

  // ---- combine: group 1 publishes partials via the dead K/V LDS buffers ----
  float* Ob = (float*)&Ks[0][0][0];  // [128 q][64 d] fp32 = 32 KB
  float* Ml = (float*)&Vs[0][0][0];  // [128 q][2] (m, l)
  const int ql0 = wvg * 32 + lrow;   // q_local of half 0; half 1 = +16

  if (grp == 1) {
#pragma unroll
    for (int df = 0; df < 4; ++df) {
      *(f32x4*)(Ob + ql0 * 64 + df * 16 + lq * 4)        = o0[df];
      *(f32x4*)(Ob + (ql0 + 16) * 64 + df * 16 + lq * 4) = o1[df];
    }
    Ml[ql0 * 2] = mrun0;        Ml[ql0 * 2 + 1] = lrun0;
    Ml[(ql0 + 16) * 2] = mrun1; Ml[(ql0 + 16) * 2 + 1] = lrun1;
  }
  __syncthreads();
  if (grp == 0) {
    // merge half 0
    {
      float m1 = Ml[ql0 * 2], l1 = Ml[ql0 * 2 + 1];
      float m  = fmaxf(mrun0, m1);
      float w0 = __builtin_amdgcn_exp2f(mrun0 - m);
      float w1 = __builtin_amdgcn_exp2f(m1 - m);
      float inv = 1.0f / (lrun0 * w0 + l1 * w1);
      ushortT* ob = O + (size_t)(q0 + ql0) * EMBED + h * HD;
#pragma unroll
      for (int df = 0; df < 4; ++df) {
        f32x4 p1 = *(const f32x4*)(Ob + ql0 * 64 + df * 16 + lq * 4);
        uint2 w;
        w.x = (unsigned)f2bf((o0[df][0] * w0 + p1[0] * w1) * inv) |
              ((unsigned)f2bf((o0[df][1] * w0 + p1[1] * w1) * inv) << 16);
        w.y = (unsigned)f2bf((o0[df][2] * w0 + p1[2] * w1) * inv) |
              ((unsigned)f2bf((o0[df][3] * w0 + p1[3] * w1) * inv) << 16);
        *(uint2*)(ob + df * 16 + lq * 4) = w;
      }
    }
    // merge half 1
    {
      float m1 = Ml[(ql0 + 16) * 2], l1 = Ml[(ql0 + 16) * 2 + 1];
      float m  = fmaxf(mrun1, m1);
      float w0 = __builtin_amdgcn_exp2f(mrun1 - m);
      float w1 = __builtin_amdgcn_exp2f(m1 - m);
      float inv = 1.0f / (lrun1 * w0 + l1 * w1);
      ushortT* ob = O + (size_t)(q0 + ql0 + 16) * EMBED + h * HD;
#pragma unroll
      for (int df = 0; df < 4; ++df) {
        f32x4 p1 = *(const f32x4*)(Ob + (ql0 + 16) * 64 + df * 16 + lq * 4);
        uint2 w;
        w.x = (unsigned)f2bf((o1[df][0] * w0 + p1[0] * w1) * inv) |
              ((unsigned)f2bf((o1[df][1] * w0 + p1[1] * w1) * inv) << 16);
        w.y = (unsigned)f2bf((o1[df][2] * w0 + p1[2] * w1) * inv) |
              ((unsigned)f2bf((o1[df][3] * w0 + p1[3] * w1) * inv) << 16);
        *(uint2*)(ob + df * 16 + lq * 4) = w;
      }
    }
  }
}

// ---------------- metric = mean over heads of K ----------------
__global__ void metric_k(const ushortT* __restrict__ Kb, float* __restrict__ out) {
  int idx = blockIdx.x * blockDim.x + threadIdx.x;   // t*8 + c8
  int t = idx >> 3, c8 = idx & 7;
  float acc[8] = {};
#pragma unroll
  for (int h = 0; h < HEADS; ++h) {
    short8 v = *(const short8*)(Kb + ((size_t)h * L_SEQ + t) * HD + c8 * 8);
#pragma unroll
    for (int j = 0; j < 8; ++j) acc[j] += bf2f((ushortT)v[j]);
  }
  float* dst = out + (size_t)t * HD + c8 * 8;
#pragma unroll
  for (int j = 0; j < 8; ++j) dst[j] = acc[j] * (1.0f / 16.0f);
}

extern "C" void kernel_launch(void* const* d_in, const int* in_sizes, int n_in,
                              void* d_out, int out_size, void* d_ws, size_t ws_size,
                              hipStream_t stream) {
  const float* hs = (const float*)d_in[0];
  const float* sz = (const float*)d_in[1];
  const float* wq = (const float*)d_in[2];
  const float* bq = (const float*)d_in[3];
  const float* wk = (const float*)d_in[4];
  const float* bk = (const float*)d_in[5];
  const float* wv = (const float*)d_in[6];
  const float* bv = (const float*)d_in[7];
  const float* wo = (const float*)d_in[8];
  const float* bo = (const float*)d_in[9];

  char* ws = (char*)d_ws;
  ushortT* hs_b = (ushortT*)(ws);                 // [4096][1024] bf16
  ushortT* wq_b = (ushortT*)(ws + (8u << 20));    // 4 weights bf16 (contiguous)
  ushortT* wk_b = wq_b + (1u << 20);
  ushortT* wv_b = wq_b + (2u << 20);
  ushortT* wo_b = wq_b + (3u << 20);
  ushortT* q_b  = (ushortT*)(ws + (16u << 20));   // [16][4096][64]
  ushortT* k_b  = (ushortT*)(ws + (24u << 20));   // [16][4096][64]
  ushortT* vt_b = (ushortT*)(ws + (32u << 20));   // [16][64][4096]
  ushortT* at_b = (ushortT*)(ws + (40u << 20));   // [4096][1024]
  float*   l2s  = (float*)(ws + (48u << 20));     // [4096]

  float* outp    = (float*)d_out;
  float* metricp = outp + (size_t)L_SEQ * EMBED;

  prep_k<<<4112, 256, 0, stream>>>(hs, wq, wk, wv, wo, sz, hs_b, wq_b, l2s);

  GemmArgs aq{wq_b, bq, (void*)q_b, 0};
  GemmArgs ak{wk_b, bk, (void*)k_b, 1};
  GemmArgs av{wv_b, bv, (void*)vt_b, 2};
  gemm_bt_k<<<dim3(256, 3), 256, 0, stream>>>(hs_b, aq, ak, av);   // fused QKV

  attn_k<<<512, 512, 0, stream>>>(q_b, k_b, vt_b, l2s, at_b);

  gemm_o64_k<<<512, 256, 0, stream>>>(at_b, wo_b, bo, outp);       // O projection

  metric_k<<<L_SEQ * 8 / 256, 256, 0, stream>>>(k_b, metricp);     // overlaps o64 drain
}